// Round 10
// baseline (197.028 us; speedup 1.0000x reference)
//
#include <hip/hip_runtime.h>
#include <stdint.h>

typedef unsigned short u16;
typedef __attribute__((ext_vector_type(8))) short short8;
typedef __attribute__((ext_vector_type(8))) u16 ushort8;
typedef __attribute__((ext_vector_type(4))) float f32x4;
typedef __attribute__((ext_vector_type(16))) float f32x16;
typedef __attribute__((ext_vector_type(4))) unsigned int uint4v;

#define LOG2E 1.44269504088896f

__device__ __forceinline__ u16 f2bf(float f) {
  unsigned int u = __builtin_bit_cast(unsigned int, f);
  u += 0x7FFF + ((u >> 16) & 1);  // RNE; inputs finite
  return (u16)(u >> 16);
}
// HW packed f32->bf16 (RNE): lo = a, hi = b.
__device__ __forceinline__ unsigned int cvtpk(float a, float b) {
  unsigned int r;
  asm("v_cvt_pk_bf16_f32 %0, %1, %2" : "=v"(r) : "v"(a), "v"(b));
  return r;
}
// v_permlane32_swap_b32: a.hi32lanes <-> b.lo32lanes.
__device__ __forceinline__ void plswap(unsigned int& a, unsigned int& b) {
  asm("v_permlane32_swap_b32 %0, %1" : "+v"(a), "+v"(b));
}
__device__ __forceinline__ void gload_lds16(const u16* g, u16* l) {
  __builtin_amdgcn_global_load_lds((const __attribute__((address_space(1))) void*)g,
                                   (__attribute__((address_space(3))) void*)l, 16, 0, 0);
}

// ---------------- fused fp32 -> bf16 convert (all 5 tensors, 1 launch) ----------
__global__ __launch_bounds__(256) void cvt_all(
    const float* __restrict__ s0, u16* __restrict__ d0, int n0,
    const float* __restrict__ s1, u16* __restrict__ d1, int n1,
    const float* __restrict__ s2, u16* __restrict__ d2, int n2,
    const float* __restrict__ s3, u16* __restrict__ d3, int n3,
    const float* __restrict__ s4, u16* __restrict__ d4, int n4) {
  const int tid0 = blockIdx.x * 256 + threadIdx.x;
  const int stride = gridDim.x * 256 * 4;
#define CVT_SEG(S, D, N)                                       \
  for (int i = tid0 * 4; i < (N); i += stride) {               \
    float4 v = *(const float4*)((S) + i);                      \
    *(uint2*)((D) + i) = make_uint2(cvtpk(v.x, v.y), cvtpk(v.z, v.w)); \
  }
  CVT_SEG(s0, d0, n0)
  CVT_SEG(s1, d1, n1)
  CVT_SEG(s2, d2, n2)
  CVT_SEG(s3, d3, n3)
  CVT_SEG(s4, d4, n4)
#undef CVT_SEG
}

// ---------------- 128x128 bf16 GEMM, C = A * B^T (+bias) ----------------
// 2-PHASE double-buffered K-loop (T3-minimum); LDS XOR-swizzled (T2).
// MODE 0: qkv epilogue -> FRAGMENT-MAJOR packed q/k/v (q pre-scaled by
//         0.125*log2e so attention uses exp2). MODE 1: proj -> fp32 out.
#define CTS 130  // ct row stride (u16): bank step 65 == 1 mod 32
template <int MODE>
__global__ __launch_bounds__(256) void gemm128(
    const u16* __restrict__ A, const u16* __restrict__ B,
    const float* __restrict__ bias,
    u16* __restrict__ qo, u16* __restrict__ ko, u16* __restrict__ vto,
    float* __restrict__ fout, int M, int N, int K) {
  __shared__ u16 smem[4 * 128 * 64];  // [2 dbuf][A,B] 64 KB; epilogue reuses as ct
  const int tid = threadIdx.x;
  const int lane = tid & 63, wave = tid >> 6;
  const int wr = wave >> 1, wc = wave & 1;
  const int l15 = lane & 15, l4 = lane >> 4;
  const int bm = blockIdx.y << 7, bn = blockIdx.x << 7;
  f32x4 acc[4][4] = {};
  const int nkt = K >> 6;

#define STAGE(buf, kt)                                                        \
  {                                                                           \
    u16* As_ = smem + (buf) * 16384;                                          \
    u16* Bs_ = As_ + 8192;                                                    \
    const int k0_ = (kt) << 6;                                                \
    _Pragma("unroll") for (int j = 0; j < 4; ++j) {                           \
      const int cbase = j * 256 + wave * 64;                                  \
      const int chunk = cbase + lane;                                         \
      const int row = chunk >> 3;                                             \
      const int co = (((chunk & 7) ^ (row & 7)) << 3);                        \
      gload_lds16(A + (size_t)(bm + row) * K + k0_ + co, As_ + cbase * 8);    \
      gload_lds16(B + (size_t)(bn + row) * K + k0_ + co, Bs_ + cbase * 8);    \
    }                                                                         \
  }

  STAGE(0, 0)
  __syncthreads();  // vmcnt(0) drain: buf0 ready
  int cur = 0;
  for (int kt = 0; kt < nkt; ++kt) {
    if (kt + 1 < nkt) STAGE(cur ^ 1, kt + 1)  // prefetch next tile
    const u16* As = smem + cur * 16384;
    const u16* Bs = As + 8192;
    short8 af[2][4], bf[2][4];
#pragma unroll
    for (int kc = 0; kc < 2; ++kc)
#pragma unroll
      for (int i = 0; i < 4; ++i) {
        const int rA = wr * 64 + i * 16 + l15;
        const int rB = wc * 64 + i * 16 + l15;
        af[kc][i] = *(const short8*)((const char*)As +
            (((rA * 64 + kc * 32 + l4 * 8) * 2) ^ ((rA & 7) << 4)));
        bf[kc][i] = *(const short8*)((const char*)Bs +
            (((rB * 64 + kc * 32 + l4 * 8) * 2) ^ ((rB & 7) << 4)));
      }
#pragma unroll
    for (int kc = 0; kc < 2; ++kc)
#pragma unroll
      for (int mi = 0; mi < 4; ++mi)
#pragma unroll
        for (int ni = 0; ni < 4; ++ni)
          acc[mi][ni] = __builtin_amdgcn_mfma_f32_16x16x32_bf16(
              af[kc][mi], bf[kc][ni], acc[mi][ni], 0, 0, 0);
    __syncthreads();  // drains prefetch (vmcnt 0) + all reads of cur done
    cur ^= 1;
  }
#undef STAGE

  if (MODE == 1) {
#pragma unroll
    for (int ni = 0; ni < 4; ++ni) {
      const int col = wc * 64 + ni * 16 + l15;
      const float bv = bias[bn + col];
#pragma unroll
      for (int mi = 0; mi < 4; ++mi)
#pragma unroll
        for (int j = 0; j < 4; ++j) {
          const int row = wr * 64 + mi * 16 + l4 * 4 + j;
          fout[(size_t)(bm + row) * N + bn + col] = acc[mi][ni][j] + bv;
        }
    }
    return;
  }
  // MODE 0: stage C tile to LDS as bf16, then scatter to packed layouts
  u16* ct = smem;  // [128][CTS]  (loop ended with a barrier)
  const int which = bn / 768;  // 0:q 1:k 2:v (768 = 6*128, boundaries align)
  const float sc = (which == 0) ? 0.125f * LOG2E : 1.0f;  // SDPA scale + log2e fold
#pragma unroll
  for (int ni = 0; ni < 4; ++ni) {
    const int col = wc * 64 + ni * 16 + l15;
    const float bv = bias[bn + col];
#pragma unroll
    for (int mi = 0; mi < 4; ++mi)
#pragma unroll
      for (int j = 0; j < 4; ++j) {
        const int row = wr * 64 + mi * 16 + l4 * 4 + j;
        ct[row * CTS + col] = f2bf((acc[mi][ni][j] + bv) * sc);
      }
  }
  __syncthreads();
  const int nrel = bn - which * 768;
  const int head0 = nrel >> 6;  // 128-wide tile covers exactly 2 heads
  const int b = bm >> 10;       // 128-row tile stays inside one batch
  if (which < 2) {
    u16* dst0 = which ? ko : qo;
    const int row = tid >> 1, hp = tid & 1;  // hp selects head parity
    const int head = head0 + hp;
    const int pos = (bm + row) & 1023;
    const u16* s = ct + row * CTS + hp * 64;
    u16* base = dst0 + ((size_t)(b * 12 + head)) * 65536;
    if (which == 0) {
      const int qsub = pos >> 5, lq = pos & 31;
#pragma unroll
      for (int g = 0; g < 8; ++g) {
        const int c = g >> 1, hi = g & 1;
        *(ushort8*)(base + ((qsub * 4 + c) * 64 + hi * 32 + lq) * 8) =
            *(const ushort8*)(s + g * 8);
      }
    } else {
      const int t = pos >> 6, hf = (pos >> 5) & 1, lq = pos & 31;
#pragma unroll
      for (int g = 0; g < 8; ++g) {
        const int c = g >> 1, hi = g & 1;
        *(ushort8*)(base + (((t * 4 + c) * 2 + hf) * 64 + hi * 32 + lq) * 8) =
            *(const ushort8*)(s + g * 8);
      }
    }
  } else {
    const int c = tid >> 1, seg = tid & 1;
    const int head = head0 + (c >> 6), dd = c & 63;
    const int posbase = (bm & 1023) + seg * 64;
    const int t = posbase >> 6;
    const int half = dd >> 5, lqd = dd & 31;
    u16* base = vto + ((size_t)(b * 12 + head)) * 65536;
    const u16* s = ct + (seg * 64) * CTS + c;
#pragma unroll
    for (int g = 0; g < 8; ++g) {
      ushort8 o;
#pragma unroll
      for (int e = 0; e < 8; ++e) o[e] = s[(g * 8 + e) * CTS];
      *(ushort8*)(base + (((t * 4 + (g >> 1)) * 2 + half) * 64 + (g & 1) * 32 + lqd) * 8) = o;
    }
  }
}

// ---------------- rel_h / rel_w via MFMA ----------------
// q is pre-scaled by 0.125*log2e; the x8 here yields log2e * bias exactly.
// Outputs PACKED: RH_p[bh][kh32][q1024], RW_p[bh][w32][q1024]
__global__ __launch_bounds__(64) void rel_kernel(
    const u16* __restrict__ pq, const u16* __restrict__ th,
    const u16* __restrict__ tw, float* __restrict__ rhp, float* __restrict__ rwp) {
  const int bh = blockIdx.x, h = blockIdx.y, type = blockIdx.z;
  const int lane = threadIdx.x & 63, lq = lane & 31, hi = lane >> 5;
  short8 qf[4];
#pragma unroll
  for (int c = 0; c < 4; ++c)
    qf[c] = *(const short8*)(pq + (size_t)bh * 65536 + ((h * 4 + c) * 64 + lane) * 8);
  if (type == 0) {
    const int tr = h - lq + 31;  // in [0,62]; bias key-h index kh == lq
    f32x16 acc{};
#pragma unroll
    for (int c = 0; c < 4; ++c) {
      short8 bfr = *(const short8*)(th + tr * 64 + c * 16 + hi * 8);
      acc = __builtin_amdgcn_mfma_f32_32x32x16_bf16(qf[c], bfr, acc, 0, 0, 0);
    }
    float* O = rhp + (size_t)bh * 32768 + lq * 1024 + h * 32;
#pragma unroll
    for (int r = 0; r < 16; ++r) {
      const int w = (r & 3) + 8 * (r >> 2) + 4 * hi;  // q-row within h-block
      O[w] = acc[r] * 8.0f;
    }
  } else {
    const int r0 = lq;                          // j = lq
    const int r1 = (lq == 31) ? 62 : (32 + lq); // j = 32+lq (clamped; lq==31 unused)
    f32x16 a0{}, a1{};
#pragma unroll
    for (int c = 0; c < 4; ++c) {
      short8 b0 = *(const short8*)(tw + r0 * 64 + c * 16 + hi * 8);
      short8 b1 = *(const short8*)(tw + r1 * 64 + c * 16 + hi * 8);
      a0 = __builtin_amdgcn_mfma_f32_32x32x16_bf16(qf[c], b0, a0, 0, 0, 0);
      a1 = __builtin_amdgcn_mfma_f32_32x32x16_bf16(qf[c], b1, a1, 0, 0, 0);
    }
    float* O = rwp + (size_t)bh * 32768 + h * 32;
#pragma unroll
    for (int r = 0; r < 16; ++r) {
      const int w = (r & 3) + 8 * (r >> 2) + 4 * hi;
      const int k0i = w - lq + 31;  // from tile j=lq
      const int k1i = w - lq - 1;   // from tile j=32+lq
      if (k0i >= 0 && k0i < 32) O[k0i * 1024 + w] = a0[r] * 8.0f;
      if (k1i >= 0) O[k1i * 1024 + w] = a1[r] * 8.0f;
    }
  }
}

// ---------------- fused attention, 4-way split-K, packed operands ----------------
// grid (48 bh, 16 qtiles64), 512 threads = 8 waves = (2 q-subtiles x 4 key-splits).
// Whole grid co-resident: 768 blocks = 3/CU x 8 waves = 24 waves/CU (75% cap).
// Each wave: 32 q rows x 256 keys (4 tiles). Tree combine:
//   stage 1: wk=2,3 dump partial O to LDS; barrier; wk=0,1 fold in.
//   stage 2: proven symmetric 2-way exchange (wk0 finalizes d0..31, wk1 d32..63).
__global__ __launch_bounds__(512, 6) void attn_kernel(
    const u16* __restrict__ pq, const u16* __restrict__ pk,
    const u16* __restrict__ pv, const float* __restrict__ rhp,
    const float* __restrict__ rwp, u16* __restrict__ aout) {
  const int bh = blockIdx.x, qt = blockIdx.y;
  const int tid = threadIdx.x, lane = tid & 63, wave = tid >> 6;
  const int wq = wave >> 2, wk = wave & 3;
  const int lq = lane & 31, hi = lane >> 5;
  const int q0 = qt * 64 + wq * 32;
  const u16* Qb = pq + (size_t)bh * 65536;
  const u16* Kb = pk + (size_t)bh * 65536;
  const u16* Vb = pv + (size_t)bh * 65536;
  const float* RH = rhp + (size_t)bh * 32768;
  const float* RW = rwp + (size_t)bh * 32768;
  __shared__ float S1[2][2][64][33];   // stride 33: (lane+elem)%32 conflict-free
  __shared__ float lsums[2][4][32];
  const int qg = q0 + lq;  // this lane's q row
  const int qsub = qt * 2 + wq;
  short8 qf[4];
#pragma unroll
  for (int c = 0; c < 4; ++c)
    qf[c] = *(const short8*)(Qb + ((qsub * 4 + c) * 64 + lane) * 8);
  float rw[16];
#pragma unroll
  for (int r = 0; r < 16; ++r)
    rw[r] = RW[((r & 3) + 8 * (r >> 2) + 4 * hi) * 1024 + qg];
  f32x16 o0{}, o1{};
  float lsum = 0.f;
  for (int t = 0; t < 4; ++t) {
    const int tt = wk * 4 + t;
    // V loads issued early: latency hides under QK^T + exp
    short8 vb0[4], vb1[4];
#pragma unroll
    for (int cc = 0; cc < 4; ++cc) {
      vb0[cc] = *(const short8*)(Vb + (((tt * 4 + cc) * 2 + 0) * 64 + lane) * 8);
      vb1[cc] = *(const short8*)(Vb + (((tt * 4 + cc) * 2 + 1) * 64 + lane) * 8);
    }
    const float rh0 = RH[(tt * 2) * 1024 + qg];
    const float rh1 = RH[(tt * 2 + 1) * 1024 + qg];
    f32x16 s0, s1;
#pragma unroll
    for (int r = 0; r < 16; ++r) { s0[r] = rh0 + rw[r]; s1[r] = rh1 + rw[r]; }
#pragma unroll
    for (int c = 0; c < 4; ++c) {
      short8 ka = *(const short8*)(Kb + (((tt * 4 + c) * 2 + 0) * 64 + lane) * 8);
      short8 kb2 = *(const short8*)(Kb + (((tt * 4 + c) * 2 + 1) * 64 + lane) * 8);
      s0 = __builtin_amdgcn_mfma_f32_32x32x16_bf16(ka, qf[c], s0, 0, 0, 0);
      s1 = __builtin_amdgcn_mfma_f32_32x32x16_bf16(kb2, qf[c], s1, 0, 0, 0);
    }
    // |S'| <= ~4.5 -> exp2 without max-subtract (log2e folded upstream)
#pragma unroll
    for (int r = 0; r < 16; ++r) { s0[r] = exp2f(s0[r]); s1[r] = exp2f(s1[r]); }
#pragma unroll
    for (int r = 0; r < 16; ++r) lsum += s0[r] + s1[r];
    // HW pack to bf16 + permlane half-exchange -> PV A-fragments (T12)
    unsigned int pw[16];
#pragma unroll
    for (int j = 0; j < 8; ++j) pw[j] = cvtpk(s0[2 * j], s0[2 * j + 1]);
#pragma unroll
    for (int j = 0; j < 8; ++j) pw[8 + j] = cvtpk(s1[2 * j], s1[2 * j + 1]);
    plswap(pw[0], pw[2]);  plswap(pw[1], pw[3]);
    plswap(pw[4], pw[6]);  plswap(pw[5], pw[7]);
    plswap(pw[8], pw[10]); plswap(pw[9], pw[11]);
    plswap(pw[12], pw[14]); plswap(pw[13], pw[15]);
#pragma unroll
    for (int cc = 0; cc < 4; ++cc) {
      uint4v w4 = {pw[cc * 4 + 0], pw[cc * 4 + 1], pw[cc * 4 + 2], pw[cc * 4 + 3]};
      short8 pa = __builtin_bit_cast(short8, w4);
      o0 = __builtin_amdgcn_mfma_f32_32x32x16_bf16(pa, vb0[cc], o0, 0, 0, 0);
      o1 = __builtin_amdgcn_mfma_f32_32x32x16_bf16(pa, vb1[cc], o1, 0, 0, 0);
    }
  }
  lsum += __shfl_xor(lsum, 32, 64);
  if (hi == 0) lsums[wq][wk][lq] = lsum;
  // stage 1: upper key-splits dump both O halves (wk2 -> slot0, wk3 -> slot1)
  if (wk >= 2) {
#pragma unroll
    for (int r = 0; r < 16; ++r) {
      S1[wq][wk - 2][lane][r] = o0[r];
      S1[wq][wk - 2][lane][16 + r] = o1[r];
    }
  }
  __syncthreads();
  if (wk < 2) {
    // fold partner split (wk0 += wk2, wk1 += wk3)
#pragma unroll
    for (int r = 0; r < 16; ++r) {
      o0[r] += S1[wq][wk][lane][r];
      o1[r] += S1[wq][wk][lane][16 + r];
    }
    // stage 2: store the half this wave will NOT finalize into its OWN slot
    // (alias-safe: each wave only re-reads the slot it just consumed)
#pragma unroll
    for (int r = 0; r < 16; ++r)
      S1[wq][wk][lane][r] = wk ? o0[r] : o1[r];
  }
  __syncthreads();
  if (wk < 2) {
    const int b = bh / 12, head = bh - b * 12;
    u16* outp = aout + (size_t)b * 1024 * 768 + head * 64 + wk * 32;
#pragma unroll
    for (int r = 0; r < 16; ++r) {
      const int qr = (r & 3) + 8 * (r >> 2) + 4 * hi;
      const float inv = 1.0f / (lsums[wq][0][qr] + lsums[wq][1][qr] +
                                lsums[wq][2][qr] + lsums[wq][3][qr]);
      const float own = wk ? o1[r] : o0[r];
      const float val = own + S1[wq][wk ^ 1][lane][r];
      outp[(size_t)(q0 + qr) * 768 + lq] = f2bf(val * inv);
    }
  }
}

// ---------------- launch ----------------
extern "C" void kernel_launch(void* const* d_in, const int* in_sizes, int n_in,
                              void* d_out, int out_size, void* d_ws, size_t ws_size,
                              hipStream_t stream) {
  const float* x = (const float*)d_in[0];
  const float* qkv_w = (const float*)d_in[1];
  const float* qkv_b = (const float*)d_in[2];
  const float* proj_w = (const float*)d_in[3];
  const float* proj_b = (const float*)d_in[4];
  const float* rph = (const float*)d_in[5];
  const float* rpw = (const float*)d_in[6];
  float* out = (float*)d_out;
  char* ws = (char*)d_ws;
  u16* xb     = (u16*)(ws + 0);
  u16* wqkv   = (u16*)(ws + 6291456);
  u16* wproj  = (u16*)(ws + 9830400);
  u16* pq     = (u16*)(ws + 11010048);
  u16* pk     = (u16*)(ws + 17301504);
  u16* pv     = (u16*)(ws + 23592960);
  float* rhp  = (float*)(ws + 29884416);
  float* rwp  = (float*)(ws + 36175872);
  u16* aout   = (u16*)(ws + 42467328);
  u16* rphb   = (u16*)(ws + 48758784);
  u16* rpwb   = (u16*)(ws + 48766848);

  cvt_all<<<1024, 256, 0, stream>>>(x, xb, 3145728, qkv_w, wqkv, 1769472,
                                    proj_w, wproj, 589824, rph, rphb, 4032,
                                    rpw, rpwb, 4032);
  gemm128<0><<<dim3(18, 32), 256, 0, stream>>>(xb, wqkv, qkv_b, pq, pk, pv,
                                               nullptr, 4096, 2304, 768);
  rel_kernel<<<dim3(48, 32, 2), 64, 0, stream>>>(pq, rphb, rpwb, rhp, rwp);
  attn_kernel<<<dim3(48, 16), 512, 0, stream>>>(pq, pk, pv, rhp, rwp, aout);
  gemm128<1><<<dim3(6, 32), 256, 0, stream>>>(aout, wproj, proj_b, nullptr, nullptr,
                                              nullptr, out, 4096, 768, 768);
}

// Round 11
// 101.904 us; speedup vs baseline: 1.9335x; 1.9335x over previous
//
#include <hip/hip_runtime.h>
#include <stdint.h>

typedef unsigned short u16;
typedef __attribute__((ext_vector_type(8))) short short8;
typedef __attribute__((ext_vector_type(8))) u16 ushort8;
typedef __attribute__((ext_vector_type(4))) float f32x4;
typedef __attribute__((ext_vector_type(16))) float f32x16;
typedef __attribute__((ext_vector_type(4))) unsigned int uint4v;

#define LOG2E 1.44269504088896f

__device__ __forceinline__ u16 f2bf(float f) {
  unsigned int u = __builtin_bit_cast(unsigned int, f);
  u += 0x7FFF + ((u >> 16) & 1);  // RNE; inputs finite
  return (u16)(u >> 16);
}
// HW packed f32->bf16 (RNE): lo = a, hi = b.
__device__ __forceinline__ unsigned int cvtpk(float a, float b) {
  unsigned int r;
  asm("v_cvt_pk_bf16_f32 %0, %1, %2" : "=v"(r) : "v"(a), "v"(b));
  return r;
}
// v_permlane32_swap_b32: a.hi32lanes <-> b.lo32lanes.
__device__ __forceinline__ void plswap(unsigned int& a, unsigned int& b) {
  asm("v_permlane32_swap_b32 %0, %1" : "+v"(a), "+v"(b));
}
__device__ __forceinline__ void gload_lds16(const u16* g, u16* l) {
  __builtin_amdgcn_global_load_lds((const __attribute__((address_space(1))) void*)g,
                                   (__attribute__((address_space(3))) void*)l, 16, 0, 0);
}

// ---------------- fused fp32 -> bf16 convert (all 5 tensors, 1 launch) ----------
__global__ __launch_bounds__(256) void cvt_all(
    const float* __restrict__ s0, u16* __restrict__ d0, int n0,
    const float* __restrict__ s1, u16* __restrict__ d1, int n1,
    const float* __restrict__ s2, u16* __restrict__ d2, int n2,
    const float* __restrict__ s3, u16* __restrict__ d3, int n3,
    const float* __restrict__ s4, u16* __restrict__ d4, int n4) {
  const int tid0 = blockIdx.x * 256 + threadIdx.x;
  const int stride = gridDim.x * 256 * 4;
#define CVT_SEG(S, D, N)                                       \
  for (int i = tid0 * 4; i < (N); i += stride) {               \
    float4 v = *(const float4*)((S) + i);                      \
    *(uint2*)((D) + i) = make_uint2(cvtpk(v.x, v.y), cvtpk(v.z, v.w)); \
  }
  CVT_SEG(s0, d0, n0)
  CVT_SEG(s1, d1, n1)
  CVT_SEG(s2, d2, n2)
  CVT_SEG(s3, d3, n3)
  CVT_SEG(s4, d4, n4)
#undef CVT_SEG
}

// ---------------- 128x128 bf16 GEMM, C = A * B^T (+bias) ----------------
// 2-PHASE double-buffered K-loop (T3-minimum); LDS XOR-swizzled (T2).
// MODE 0: qkv epilogue -> FRAGMENT-MAJOR packed q/k/v (q pre-scaled by
//         0.125*log2e so attention uses exp2). MODE 1: proj -> fp32 out.
#define CTS 130  // ct row stride (u16): bank step 65 == 1 mod 32
template <int MODE>
__global__ __launch_bounds__(256) void gemm128(
    const u16* __restrict__ A, const u16* __restrict__ B,
    const float* __restrict__ bias,
    u16* __restrict__ qo, u16* __restrict__ ko, u16* __restrict__ vto,
    float* __restrict__ fout, int M, int N, int K) {
  __shared__ u16 smem[4 * 128 * 64];  // [2 dbuf][A,B] 64 KB; epilogue reuses as ct
  const int tid = threadIdx.x;
  const int lane = tid & 63, wave = tid >> 6;
  const int wr = wave >> 1, wc = wave & 1;
  const int l15 = lane & 15, l4 = lane >> 4;
  const int bm = blockIdx.y << 7, bn = blockIdx.x << 7;
  f32x4 acc[4][4] = {};
  const int nkt = K >> 6;

#define STAGE(buf, kt)                                                        \
  {                                                                           \
    u16* As_ = smem + (buf) * 16384;                                          \
    u16* Bs_ = As_ + 8192;                                                    \
    const int k0_ = (kt) << 6;                                                \
    _Pragma("unroll") for (int j = 0; j < 4; ++j) {                           \
      const int cbase = j * 256 + wave * 64;                                  \
      const int chunk = cbase + lane;                                         \
      const int row = chunk >> 3;                                             \
      const int co = (((chunk & 7) ^ (row & 7)) << 3);                        \
      gload_lds16(A + (size_t)(bm + row) * K + k0_ + co, As_ + cbase * 8);    \
      gload_lds16(B + (size_t)(bn + row) * K + k0_ + co, Bs_ + cbase * 8);    \
    }                                                                         \
  }

  STAGE(0, 0)
  __syncthreads();  // vmcnt(0) drain: buf0 ready
  int cur = 0;
  for (int kt = 0; kt < nkt; ++kt) {
    if (kt + 1 < nkt) STAGE(cur ^ 1, kt + 1)  // prefetch next tile
    const u16* As = smem + cur * 16384;
    const u16* Bs = As + 8192;
    short8 af[2][4], bf[2][4];
#pragma unroll
    for (int kc = 0; kc < 2; ++kc)
#pragma unroll
      for (int i = 0; i < 4; ++i) {
        const int rA = wr * 64 + i * 16 + l15;
        const int rB = wc * 64 + i * 16 + l15;
        af[kc][i] = *(const short8*)((const char*)As +
            (((rA * 64 + kc * 32 + l4 * 8) * 2) ^ ((rA & 7) << 4)));
        bf[kc][i] = *(const short8*)((const char*)Bs +
            (((rB * 64 + kc * 32 + l4 * 8) * 2) ^ ((rB & 7) << 4)));
      }
#pragma unroll
    for (int kc = 0; kc < 2; ++kc)
#pragma unroll
      for (int mi = 0; mi < 4; ++mi)
#pragma unroll
        for (int ni = 0; ni < 4; ++ni)
          acc[mi][ni] = __builtin_amdgcn_mfma_f32_16x16x32_bf16(
              af[kc][mi], bf[kc][ni], acc[mi][ni], 0, 0, 0);
    __syncthreads();  // drains prefetch (vmcnt 0) + all reads of cur done
    cur ^= 1;
  }
#undef STAGE

  if (MODE == 1) {
#pragma unroll
    for (int ni = 0; ni < 4; ++ni) {
      const int col = wc * 64 + ni * 16 + l15;
      const float bv = bias[bn + col];
#pragma unroll
      for (int mi = 0; mi < 4; ++mi)
#pragma unroll
        for (int j = 0; j < 4; ++j) {
          const int row = wr * 64 + mi * 16 + l4 * 4 + j;
          fout[(size_t)(bm + row) * N + bn + col] = acc[mi][ni][j] + bv;
        }
    }
    return;
  }
  // MODE 0: stage C tile to LDS as bf16, then scatter to packed layouts
  u16* ct = smem;  // [128][CTS]  (loop ended with a barrier)
  const int which = bn / 768;  // 0:q 1:k 2:v (768 = 6*128, boundaries align)
  const float sc = (which == 0) ? 0.125f * LOG2E : 1.0f;  // SDPA scale + log2e fold
#pragma unroll
  for (int ni = 0; ni < 4; ++ni) {
    const int col = wc * 64 + ni * 16 + l15;
    const float bv = bias[bn + col];
#pragma unroll
    for (int mi = 0; mi < 4; ++mi)
#pragma unroll
      for (int j = 0; j < 4; ++j) {
        const int row = wr * 64 + mi * 16 + l4 * 4 + j;
        ct[row * CTS + col] = f2bf((acc[mi][ni][j] + bv) * sc);
      }
  }
  __syncthreads();
  const int nrel = bn - which * 768;
  const int head0 = nrel >> 6;  // 128-wide tile covers exactly 2 heads
  const int b = bm >> 10;       // 128-row tile stays inside one batch
  if (which < 2) {
    u16* dst0 = which ? ko : qo;
    const int row = tid >> 1, hp = tid & 1;  // hp selects head parity
    const int head = head0 + hp;
    const int pos = (bm + row) & 1023;
    const u16* s = ct + row * CTS + hp * 64;
    u16* base = dst0 + ((size_t)(b * 12 + head)) * 65536;
    if (which == 0) {
      const int qsub = pos >> 5, lq = pos & 31;
#pragma unroll
      for (int g = 0; g < 8; ++g) {
        const int c = g >> 1, hi = g & 1;
        *(ushort8*)(base + ((qsub * 4 + c) * 64 + hi * 32 + lq) * 8) =
            *(const ushort8*)(s + g * 8);
      }
    } else {
      const int t = pos >> 6, hf = (pos >> 5) & 1, lq = pos & 31;
#pragma unroll
      for (int g = 0; g < 8; ++g) {
        const int c = g >> 1, hi = g & 1;
        *(ushort8*)(base + (((t * 4 + c) * 2 + hf) * 64 + hi * 32 + lq) * 8) =
            *(const ushort8*)(s + g * 8);
      }
    }
  } else {
    const int c = tid >> 1, seg = tid & 1;
    const int head = head0 + (c >> 6), dd = c & 63;
    const int posbase = (bm & 1023) + seg * 64;
    const int t = posbase >> 6;
    const int half = dd >> 5, lqd = dd & 31;
    u16* base = vto + ((size_t)(b * 12 + head)) * 65536;
    const u16* s = ct + (seg * 64) * CTS + c;
#pragma unroll
    for (int g = 0; g < 8; ++g) {
      ushort8 o;
#pragma unroll
      for (int e = 0; e < 8; ++e) o[e] = s[(g * 8 + e) * CTS];
      *(ushort8*)(base + (((t * 4 + (g >> 1)) * 2 + half) * 64 + (g & 1) * 32 + lqd) * 8) = o;
    }
  }
}

// ---------------- rel_h / rel_w via MFMA ----------------
// q is pre-scaled by 0.125*log2e; the x8 here yields log2e * bias exactly.
// Outputs PACKED: RH_p[bh][kh32][q1024], RW_p[bh][w32][q1024]
__global__ __launch_bounds__(64) void rel_kernel(
    const u16* __restrict__ pq, const u16* __restrict__ th,
    const u16* __restrict__ tw, float* __restrict__ rhp, float* __restrict__ rwp) {
  const int bh = blockIdx.x, h = blockIdx.y, type = blockIdx.z;
  const int lane = threadIdx.x & 63, lq = lane & 31, hi = lane >> 5;
  short8 qf[4];
#pragma unroll
  for (int c = 0; c < 4; ++c)
    qf[c] = *(const short8*)(pq + (size_t)bh * 65536 + ((h * 4 + c) * 64 + lane) * 8);
  if (type == 0) {
    const int tr = h - lq + 31;  // in [0,62]; bias key-h index kh == lq
    f32x16 acc{};
#pragma unroll
    for (int c = 0; c < 4; ++c) {
      short8 bfr = *(const short8*)(th + tr * 64 + c * 16 + hi * 8);
      acc = __builtin_amdgcn_mfma_f32_32x32x16_bf16(qf[c], bfr, acc, 0, 0, 0);
    }
    float* O = rhp + (size_t)bh * 32768 + lq * 1024 + h * 32;
#pragma unroll
    for (int r = 0; r < 16; ++r) {
      const int w = (r & 3) + 8 * (r >> 2) + 4 * hi;  // q-row within h-block
      O[w] = acc[r] * 8.0f;
    }
  } else {
    const int r0 = lq;                          // j = lq
    const int r1 = (lq == 31) ? 62 : (32 + lq); // j = 32+lq (clamped; lq==31 unused)
    f32x16 a0{}, a1{};
#pragma unroll
    for (int c = 0; c < 4; ++c) {
      short8 b0 = *(const short8*)(tw + r0 * 64 + c * 16 + hi * 8);
      short8 b1 = *(const short8*)(tw + r1 * 64 + c * 16 + hi * 8);
      a0 = __builtin_amdgcn_mfma_f32_32x32x16_bf16(qf[c], b0, a0, 0, 0, 0);
      a1 = __builtin_amdgcn_mfma_f32_32x32x16_bf16(qf[c], b1, a1, 0, 0, 0);
    }
    float* O = rwp + (size_t)bh * 32768 + h * 32;
#pragma unroll
    for (int r = 0; r < 16; ++r) {
      const int w = (r & 3) + 8 * (r >> 2) + 4 * hi;
      const int k0i = w - lq + 31;  // from tile j=lq
      const int k1i = w - lq - 1;   // from tile j=32+lq
      if (k0i >= 0 && k0i < 32) O[k0i * 1024 + w] = a0[r] * 8.0f;
      if (k1i >= 0) O[k1i * 1024 + w] = a1[r] * 8.0f;
    }
  }
}

// ---------------- fused attention, 4-way split-K, packed operands ----------------
// grid (48 bh, 16 qtiles64), 512 threads = 8 waves = (2 q-subtiles x 4 key-splits).
// __launch_bounds__(512, 4): min 4 waves/SIMD = 2 blocks/CU -> VGPR cap 128.
// (R10's (512,6) capped VGPR at 40 -> full accumulator spill, 285 MB scratch
// writes, 3.5x regression. The 2nd arg is waves per SIMD, not blocks per CU.)
// Tree combine: wk=2,3 dump partial O; barrier; wk=0,1 fold, then symmetric
// 2-way exchange; wk0 finalizes d0..31, wk1 d32..63.
__global__ __launch_bounds__(512, 4) void attn_kernel(
    const u16* __restrict__ pq, const u16* __restrict__ pk,
    const u16* __restrict__ pv, const float* __restrict__ rhp,
    const float* __restrict__ rwp, u16* __restrict__ aout) {
  const int bh = blockIdx.x, qt = blockIdx.y;
  const int tid = threadIdx.x, lane = tid & 63, wave = tid >> 6;
  const int wq = wave >> 2, wk = wave & 3;
  const int lq = lane & 31, hi = lane >> 5;
  const int q0 = qt * 64 + wq * 32;
  const u16* Qb = pq + (size_t)bh * 65536;
  const u16* Kb = pk + (size_t)bh * 65536;
  const u16* Vb = pv + (size_t)bh * 65536;
  const float* RH = rhp + (size_t)bh * 32768;
  const float* RW = rwp + (size_t)bh * 32768;
  __shared__ float S1[2][2][64][33];   // stride 33: (lane+elem)%32 conflict-free
  __shared__ float lsums[2][4][32];
  const int qg = q0 + lq;  // this lane's q row
  const int qsub = qt * 2 + wq;
  short8 qf[4];
#pragma unroll
  for (int c = 0; c < 4; ++c)
    qf[c] = *(const short8*)(Qb + ((qsub * 4 + c) * 64 + lane) * 8);
  float rw[16];
#pragma unroll
  for (int r = 0; r < 16; ++r)
    rw[r] = RW[((r & 3) + 8 * (r >> 2) + 4 * hi) * 1024 + qg];
  f32x16 o0{}, o1{};
  float lsum = 0.f;
  for (int t = 0; t < 4; ++t) {
    const int tt = wk * 4 + t;
    // V loads issued early: latency hides under QK^T + exp
    short8 vb0[4], vb1[4];
#pragma unroll
    for (int cc = 0; cc < 4; ++cc) {
      vb0[cc] = *(const short8*)(Vb + (((tt * 4 + cc) * 2 + 0) * 64 + lane) * 8);
      vb1[cc] = *(const short8*)(Vb + (((tt * 4 + cc) * 2 + 1) * 64 + lane) * 8);
    }
    const float rh0 = RH[(tt * 2) * 1024 + qg];
    const float rh1 = RH[(tt * 2 + 1) * 1024 + qg];
    f32x16 s0, s1;
#pragma unroll
    for (int r = 0; r < 16; ++r) { s0[r] = rh0 + rw[r]; s1[r] = rh1 + rw[r]; }
#pragma unroll
    for (int c = 0; c < 4; ++c) {
      short8 ka = *(const short8*)(Kb + (((tt * 4 + c) * 2 + 0) * 64 + lane) * 8);
      short8 kb2 = *(const short8*)(Kb + (((tt * 4 + c) * 2 + 1) * 64 + lane) * 8);
      s0 = __builtin_amdgcn_mfma_f32_32x32x16_bf16(ka, qf[c], s0, 0, 0, 0);
      s1 = __builtin_amdgcn_mfma_f32_32x32x16_bf16(kb2, qf[c], s1, 0, 0, 0);
    }
    // |S'| <= ~4.5 -> exp2 without max-subtract (log2e folded upstream)
#pragma unroll
    for (int r = 0; r < 16; ++r) { s0[r] = exp2f(s0[r]); s1[r] = exp2f(s1[r]); }
#pragma unroll
    for (int r = 0; r < 16; ++r) lsum += s0[r] + s1[r];
    // HW pack to bf16 + permlane half-exchange -> PV A-fragments (T12)
    unsigned int pw[16];
#pragma unroll
    for (int j = 0; j < 8; ++j) pw[j] = cvtpk(s0[2 * j], s0[2 * j + 1]);
#pragma unroll
    for (int j = 0; j < 8; ++j) pw[8 + j] = cvtpk(s1[2 * j], s1[2 * j + 1]);
    plswap(pw[0], pw[2]);  plswap(pw[1], pw[3]);
    plswap(pw[4], pw[6]);  plswap(pw[5], pw[7]);
    plswap(pw[8], pw[10]); plswap(pw[9], pw[11]);
    plswap(pw[12], pw[14]); plswap(pw[13], pw[15]);
#pragma unroll
    for (int cc = 0; cc < 4; ++cc) {
      uint4v w4 = {pw[cc * 4 + 0], pw[cc * 4 + 1], pw[cc * 4 + 2], pw[cc * 4 + 3]};
      short8 pa = __builtin_bit_cast(short8, w4);
      o0 = __builtin_amdgcn_mfma_f32_32x32x16_bf16(pa, vb0[cc], o0, 0, 0, 0);
      o1 = __builtin_amdgcn_mfma_f32_32x32x16_bf16(pa, vb1[cc], o1, 0, 0, 0);
    }
  }
  lsum += __shfl_xor(lsum, 32, 64);
  if (hi == 0) lsums[wq][wk][lq] = lsum;
  // stage 1: upper key-splits dump both O halves (wk2 -> slot0, wk3 -> slot1)
  if (wk >= 2) {
#pragma unroll
    for (int r = 0; r < 16; ++r) {
      S1[wq][wk - 2][lane][r] = o0[r];
      S1[wq][wk - 2][lane][16 + r] = o1[r];
    }
  }
  __syncthreads();
  if (wk < 2) {
    // fold partner split (wk0 += wk2, wk1 += wk3)
#pragma unroll
    for (int r = 0; r < 16; ++r) {
      o0[r] += S1[wq][wk][lane][r];
      o1[r] += S1[wq][wk][lane][16 + r];
    }
    // stage 2: store the half this wave will NOT finalize into its OWN slot
    // (alias-safe: each wave only re-reads the slot it just consumed)
#pragma unroll
    for (int r = 0; r < 16; ++r)
      S1[wq][wk][lane][r] = wk ? o0[r] : o1[r];
  }
  __syncthreads();
  if (wk < 2) {
    const int b = bh / 12, head = bh - b * 12;
    u16* outp = aout + (size_t)b * 1024 * 768 + head * 64 + wk * 32;
#pragma unroll
    for (int r = 0; r < 16; ++r) {
      const int qr = (r & 3) + 8 * (r >> 2) + 4 * hi;
      const float inv = 1.0f / (lsums[wq][0][qr] + lsums[wq][1][qr] +
                                lsums[wq][2][qr] + lsums[wq][3][qr]);
      const float own = wk ? o1[r] : o0[r];
      const float val = own + S1[wq][wk ^ 1][lane][r];
      outp[(size_t)(q0 + qr) * 768 + lq] = f2bf(val * inv);
    }
  }
}

// ---------------- launch ----------------
extern "C" void kernel_launch(void* const* d_in, const int* in_sizes, int n_in,
                              void* d_out, int out_size, void* d_ws, size_t ws_size,
                              hipStream_t stream) {
  const float* x = (const float*)d_in[0];
  const float* qkv_w = (const float*)d_in[1];
  const float* qkv_b = (const float*)d_in[2];
  const float* proj_w = (const float*)d_in[3];
  const float* proj_b = (const float*)d_in[4];
  const float* rph = (const float*)d_in[5];
  const float* rpw = (const float*)d_in[6];
  float* out = (float*)d_out;
  char* ws = (char*)d_ws;
  u16* xb     = (u16*)(ws + 0);
  u16* wqkv   = (u16*)(ws + 6291456);
  u16* wproj  = (u16*)(ws + 9830400);
  u16* pq     = (u16*)(ws + 11010048);
  u16* pk     = (u16*)(ws + 17301504);
  u16* pv     = (u16*)(ws + 23592960);
  float* rhp  = (float*)(ws + 29884416);
  float* rwp  = (float*)(ws + 36175872);
  u16* aout   = (u16*)(ws + 42467328);
  u16* rphb   = (u16*)(ws + 48758784);
  u16* rpwb   = (u16*)(ws + 48766848);

  cvt_all<<<1024, 256, 0, stream>>>(x, xb, 3145728, qkv_w, wqkv, 1769472,
                                    proj_w, wproj, 589824, rph, rphb, 4032,
                                    rpw, rpwb, 4032);
  gemm128<0><<<dim3(18, 32), 256, 0, stream>>>(xb, wqkv, qkv_b, pq, pk, pv,
                                               nullptr, 4096, 2304, 768);
  rel_kernel<<<dim3(48, 32, 2), 64, 0, stream>>>(pq, rphb, rpwb, rhp, rwp);
  attn_kernel<<<dim3(48, 16), 512, 0, stream>>>(pq, pk, pv, rhp, rwp, aout);
  gemm128<1><<<dim3(6, 32), 256, 0, stream>>>(aout, wproj, proj_b, nullptr, nullptr,
                                              nullptr, out, 4096, 768, 768);
}

// Round 12
// 89.418 us; speedup vs baseline: 2.2034x; 1.1396x over previous
//
#include <hip/hip_runtime.h>
#include <stdint.h>

typedef unsigned short u16;
typedef __attribute__((ext_vector_type(8))) short short8;
typedef __attribute__((ext_vector_type(8))) u16 ushort8;
typedef __attribute__((ext_vector_type(4))) float f32x4;
typedef __attribute__((ext_vector_type(16))) float f32x16;
typedef __attribute__((ext_vector_type(4))) unsigned int uint4v;

#define LOG2E 1.44269504088896f

__device__ __forceinline__ u16 f2bf(float f) {
  unsigned int u = __builtin_bit_cast(unsigned int, f);
  u += 0x7FFF + ((u >> 16) & 1);  // RNE; inputs finite
  return (u16)(u >> 16);
}
// HW packed f32->bf16 (RNE): lo = a, hi = b.
__device__ __forceinline__ unsigned int cvtpk(float a, float b) {
  unsigned int r;
  asm("v_cvt_pk_bf16_f32 %0, %1, %2" : "=v"(r) : "v"(a), "v"(b));
  return r;
}
// v_permlane32_swap_b32: a.hi32lanes <-> b.lo32lanes.
__device__ __forceinline__ void plswap(unsigned int& a, unsigned int& b) {
  asm("v_permlane32_swap_b32 %0, %1" : "+v"(a), "+v"(b));
}
__device__ __forceinline__ void gload_lds16(const u16* g, u16* l) {
  __builtin_amdgcn_global_load_lds((const __attribute__((address_space(1))) void*)g,
                                   (__attribute__((address_space(3))) void*)l, 16, 0, 0);
}

// ---------------- fused fp32 -> bf16 convert (all 5 tensors, 1 launch) ----------
__global__ __launch_bounds__(256) void cvt_all(
    const float* __restrict__ s0, u16* __restrict__ d0, int n0,
    const float* __restrict__ s1, u16* __restrict__ d1, int n1,
    const float* __restrict__ s2, u16* __restrict__ d2, int n2,
    const float* __restrict__ s3, u16* __restrict__ d3, int n3,
    const float* __restrict__ s4, u16* __restrict__ d4, int n4) {
  const int tid0 = blockIdx.x * 256 + threadIdx.x;
  const int stride = gridDim.x * 256 * 4;
#define CVT_SEG(S, D, N)                                       \
  for (int i = tid0 * 4; i < (N); i += stride) {               \
    float4 v = *(const float4*)((S) + i);                      \
    *(uint2*)((D) + i) = make_uint2(cvtpk(v.x, v.y), cvtpk(v.z, v.w)); \
  }
  CVT_SEG(s0, d0, n0)
  CVT_SEG(s1, d1, n1)
  CVT_SEG(s2, d2, n2)
  CVT_SEG(s3, d3, n3)
  CVT_SEG(s4, d4, n4)
#undef CVT_SEG
}

// ---------------- 128x128 bf16 GEMM, C = A * B^T (+bias) ----------------
// 2-PHASE double-buffered K-loop (T3-minimum); LDS XOR-swizzled (T2).
// MODE 0: qkv epilogue -> FRAGMENT-MAJOR packed q/k/v (q pre-scaled by
//         0.125*log2e so attention uses exp2). MODE 1: proj -> fp32 out.
#define CTS 130  // ct row stride (u16): bank step 65 == 1 mod 32
template <int MODE>
__global__ __launch_bounds__(256) void gemm128(
    const u16* __restrict__ A, const u16* __restrict__ B,
    const float* __restrict__ bias,
    u16* __restrict__ qo, u16* __restrict__ ko, u16* __restrict__ vto,
    float* __restrict__ fout, int M, int N, int K) {
  __shared__ u16 smem[4 * 128 * 64];  // [2 dbuf][A,B] 64 KB; epilogue reuses as ct
  const int tid = threadIdx.x;
  const int lane = tid & 63, wave = tid >> 6;
  const int wr = wave >> 1, wc = wave & 1;
  const int l15 = lane & 15, l4 = lane >> 4;
  const int bm = blockIdx.y << 7, bn = blockIdx.x << 7;
  f32x4 acc[4][4] = {};
  const int nkt = K >> 6;

#define STAGE(buf, kt)                                                        \
  {                                                                           \
    u16* As_ = smem + (buf) * 16384;                                          \
    u16* Bs_ = As_ + 8192;                                                    \
    const int k0_ = (kt) << 6;                                                \
    _Pragma("unroll") for (int j = 0; j < 4; ++j) {                           \
      const int cbase = j * 256 + wave * 64;                                  \
      const int chunk = cbase + lane;                                         \
      const int row = chunk >> 3;                                             \
      const int co = (((chunk & 7) ^ (row & 7)) << 3);                        \
      gload_lds16(A + (size_t)(bm + row) * K + k0_ + co, As_ + cbase * 8);    \
      gload_lds16(B + (size_t)(bn + row) * K + k0_ + co, Bs_ + cbase * 8);    \
    }                                                                         \
  }

  STAGE(0, 0)
  __syncthreads();  // vmcnt(0) drain: buf0 ready
  int cur = 0;
  for (int kt = 0; kt < nkt; ++kt) {
    if (kt + 1 < nkt) STAGE(cur ^ 1, kt + 1)  // prefetch next tile
    const u16* As = smem + cur * 16384;
    const u16* Bs = As + 8192;
    short8 af[2][4], bf[2][4];
#pragma unroll
    for (int kc = 0; kc < 2; ++kc)
#pragma unroll
      for (int i = 0; i < 4; ++i) {
        const int rA = wr * 64 + i * 16 + l15;
        const int rB = wc * 64 + i * 16 + l15;
        af[kc][i] = *(const short8*)((const char*)As +
            (((rA * 64 + kc * 32 + l4 * 8) * 2) ^ ((rA & 7) << 4)));
        bf[kc][i] = *(const short8*)((const char*)Bs +
            (((rB * 64 + kc * 32 + l4 * 8) * 2) ^ ((rB & 7) << 4)));
      }
#pragma unroll
    for (int kc = 0; kc < 2; ++kc)
#pragma unroll
      for (int mi = 0; mi < 4; ++mi)
#pragma unroll
        for (int ni = 0; ni < 4; ++ni)
          acc[mi][ni] = __builtin_amdgcn_mfma_f32_16x16x32_bf16(
              af[kc][mi], bf[kc][ni], acc[mi][ni], 0, 0, 0);
    __syncthreads();  // drains prefetch (vmcnt 0) + all reads of cur done
    cur ^= 1;
  }
#undef STAGE

  if (MODE == 1) {
#pragma unroll
    for (int ni = 0; ni < 4; ++ni) {
      const int col = wc * 64 + ni * 16 + l15;
      const float bv = bias[bn + col];
#pragma unroll
      for (int mi = 0; mi < 4; ++mi)
#pragma unroll
        for (int j = 0; j < 4; ++j) {
          const int row = wr * 64 + mi * 16 + l4 * 4 + j;
          fout[(size_t)(bm + row) * N + bn + col] = acc[mi][ni][j] + bv;
        }
    }
    return;
  }
  // MODE 0: stage C tile to LDS as bf16, then scatter to packed layouts
  u16* ct = smem;  // [128][CTS]  (loop ended with a barrier)
  const int which = bn / 768;  // 0:q 1:k 2:v (768 = 6*128, boundaries align)
  const float sc = (which == 0) ? 0.125f * LOG2E : 1.0f;  // SDPA scale + log2e fold
#pragma unroll
  for (int ni = 0; ni < 4; ++ni) {
    const int col = wc * 64 + ni * 16 + l15;
    const float bv = bias[bn + col];
#pragma unroll
    for (int mi = 0; mi < 4; ++mi)
#pragma unroll
      for (int j = 0; j < 4; ++j) {
        const int row = wr * 64 + mi * 16 + l4 * 4 + j;
        ct[row * CTS + col] = f2bf((acc[mi][ni][j] + bv) * sc);
      }
  }
  __syncthreads();
  const int nrel = bn - which * 768;
  const int head0 = nrel >> 6;  // 128-wide tile covers exactly 2 heads
  const int b = bm >> 10;       // 128-row tile stays inside one batch
  if (which < 2) {
    u16* dst0 = which ? ko : qo;
    const int row = tid >> 1, hp = tid & 1;  // hp selects head parity
    const int head = head0 + hp;
    const int pos = (bm + row) & 1023;
    const u16* s = ct + row * CTS + hp * 64;
    u16* base = dst0 + ((size_t)(b * 12 + head)) * 65536;
    if (which == 0) {
      const int qsub = pos >> 5, lq = pos & 31;
#pragma unroll
      for (int g = 0; g < 8; ++g) {
        const int c = g >> 1, hi = g & 1;
        *(ushort8*)(base + ((qsub * 4 + c) * 64 + hi * 32 + lq) * 8) =
            *(const ushort8*)(s + g * 8);
      }
    } else {
      const int t = pos >> 6, hf = (pos >> 5) & 1, lq = pos & 31;
#pragma unroll
      for (int g = 0; g < 8; ++g) {
        const int c = g >> 1, hi = g & 1;
        *(ushort8*)(base + (((t * 4 + c) * 2 + hf) * 64 + hi * 32 + lq) * 8) =
            *(const ushort8*)(s + g * 8);
      }
    }
  } else {
    const int c = tid >> 1, seg = tid & 1;
    const int head = head0 + (c >> 6), dd = c & 63;
    const int posbase = (bm & 1023) + seg * 64;
    const int t = posbase >> 6;
    const int half = dd >> 5, lqd = dd & 31;
    u16* base = vto + ((size_t)(b * 12 + head)) * 65536;
    const u16* s = ct + (seg * 64) * CTS + c;
#pragma unroll
    for (int g = 0; g < 8; ++g) {
      ushort8 o;
#pragma unroll
      for (int e = 0; e < 8; ++e) o[e] = s[(g * 8 + e) * CTS];
      *(ushort8*)(base + (((t * 4 + (g >> 1)) * 2 + half) * 64 + (g & 1) * 32 + lqd) * 8) = o;
    }
  }
}

// ---------------- rel_h / rel_w via MFMA ----------------
// q is pre-scaled by 0.125*log2e; the x8 here yields log2e * bias exactly.
// Outputs PACKED: RH_p[bh][kh32][q1024], RW_p[bh][w32][q1024]
__global__ __launch_bounds__(64) void rel_kernel(
    const u16* __restrict__ pq, const u16* __restrict__ th,
    const u16* __restrict__ tw, float* __restrict__ rhp, float* __restrict__ rwp) {
  const int bh = blockIdx.x, h = blockIdx.y, type = blockIdx.z;
  const int lane = threadIdx.x & 63, lq = lane & 31, hi = lane >> 5;
  short8 qf[4];
#pragma unroll
  for (int c = 0; c < 4; ++c)
    qf[c] = *(const short8*)(pq + (size_t)bh * 65536 + ((h * 4 + c) * 64 + lane) * 8);
  if (type == 0) {
    const int tr = h - lq + 31;  // in [0,62]; bias key-h index kh == lq
    f32x16 acc{};
#pragma unroll
    for (int c = 0; c < 4; ++c) {
      short8 bfr = *(const short8*)(th + tr * 64 + c * 16 + hi * 8);
      acc = __builtin_amdgcn_mfma_f32_32x32x16_bf16(qf[c], bfr, acc, 0, 0, 0);
    }
    float* O = rhp + (size_t)bh * 32768 + lq * 1024 + h * 32;
#pragma unroll
    for (int r = 0; r < 16; ++r) {
      const int w = (r & 3) + 8 * (r >> 2) + 4 * hi;  // q-row within h-block
      O[w] = acc[r] * 8.0f;
    }
  } else {
    const int r0 = lq;                          // j = lq
    const int r1 = (lq == 31) ? 62 : (32 + lq); // j = 32+lq (clamped; lq==31 unused)
    f32x16 a0{}, a1{};
#pragma unroll
    for (int c = 0; c < 4; ++c) {
      short8 b0 = *(const short8*)(tw + r0 * 64 + c * 16 + hi * 8);
      short8 b1 = *(const short8*)(tw + r1 * 64 + c * 16 + hi * 8);
      a0 = __builtin_amdgcn_mfma_f32_32x32x16_bf16(qf[c], b0, a0, 0, 0, 0);
      a1 = __builtin_amdgcn_mfma_f32_32x32x16_bf16(qf[c], b1, a1, 0, 0, 0);
    }
    float* O = rwp + (size_t)bh * 32768 + h * 32;
#pragma unroll
    for (int r = 0; r < 16; ++r) {
      const int w = (r & 3) + 8 * (r >> 2) + 4 * hi;
      const int k0i = w - lq + 31;  // from tile j=lq
      const int k1i = w - lq - 1;   // from tile j=32+lq
      if (k0i >= 0 && k0i < 32) O[k0i * 1024 + w] = a0[r] * 8.0f;
      if (k1i >= 0) O[k1i * 1024 + w] = a1[r] * 8.0f;
    }
  }
}

// ---------------- fused attention, 2-way split-K + K-register-prefetch ----------
// grid (48 bh, 16 qtiles64), 256 threads = 4 waves = (2 q-subtiles x 2 key-halves)
// -- the proven R9 structure. NEW (T14): K fragments for tile t+1 are issued at
// the top of iteration t (full #pragma unroll -> kf[t&1] indices are static),
// so QK's first consumer sits ~1 full tile (~1500 cy) after issue -- covers
// L3 latency (~600-900 cy) that TLP (R11: 2x waves, no gain) could not.
__global__ __launch_bounds__(256) void attn_kernel(
    const u16* __restrict__ pq, const u16* __restrict__ pk,
    const u16* __restrict__ pv, const float* __restrict__ rhp,
    const float* __restrict__ rwp, u16* __restrict__ aout) {
  const int bh = blockIdx.x, qt = blockIdx.y;
  const int tid = threadIdx.x, lane = tid & 63, wave = tid >> 6;
  const int wq = wave >> 1, wk = wave & 1;
  const int lq = lane & 31, hi = lane >> 5;
  const int q0 = qt * 64 + wq * 32;
  const u16* Qb = pq + (size_t)bh * 65536;
  const u16* Kb = pk + (size_t)bh * 65536;
  const u16* Vb = pv + (size_t)bh * 65536;
  const float* RH = rhp + (size_t)bh * 32768;
  const float* RW = rwp + (size_t)bh * 32768;
  __shared__ float part[2][2][64][17];  // [wq][wk][lane][r], stride-17 pad
  __shared__ float lsums[2][2][32];
  const int qg = q0 + lq;  // this lane's q row
  const int qsub = qt * 2 + wq;
  short8 qf[4];
#pragma unroll
  for (int c = 0; c < 4; ++c)
    qf[c] = *(const short8*)(Qb + ((qsub * 4 + c) * 64 + lane) * 8);
  float rw[16];
#pragma unroll
  for (int r = 0; r < 16; ++r)
    rw[r] = RW[((r & 3) + 8 * (r >> 2) + 4 * hi) * 1024 + qg];
  f32x16 o0{}, o1{};
  float lsum = 0.f;
  short8 kf[2][8];  // [tile parity][half*4 + c] prefetched K fragments
  {
    const int t0 = wk * 8;
#pragma unroll
    for (int c = 0; c < 4; ++c) {
      kf[0][c]     = *(const short8*)(Kb + (((t0 * 4 + c) * 2 + 0) * 64 + lane) * 8);
      kf[0][4 + c] = *(const short8*)(Kb + (((t0 * 4 + c) * 2 + 1) * 64 + lane) * 8);
    }
  }
#pragma unroll
  for (int t = 0; t < 8; ++t) {
    const int tt = wk * 8 + t;
    const int cur = t & 1, nxt = cur ^ 1;
    // prefetch next tile's K (consumed one full iteration later)
    if (t < 7) {
      const int tn = tt + 1;
#pragma unroll
      for (int c = 0; c < 4; ++c) {
        kf[nxt][c]     = *(const short8*)(Kb + (((tn * 4 + c) * 2 + 0) * 64 + lane) * 8);
        kf[nxt][4 + c] = *(const short8*)(Kb + (((tn * 4 + c) * 2 + 1) * 64 + lane) * 8);
      }
    }
    // V loads issued early within the iteration: hidden under QK^T + exp
    short8 vb0[4], vb1[4];
#pragma unroll
    for (int cc = 0; cc < 4; ++cc) {
      vb0[cc] = *(const short8*)(Vb + (((tt * 4 + cc) * 2 + 0) * 64 + lane) * 8);
      vb1[cc] = *(const short8*)(Vb + (((tt * 4 + cc) * 2 + 1) * 64 + lane) * 8);
    }
    const float rh0 = RH[(tt * 2) * 1024 + qg];
    const float rh1 = RH[(tt * 2 + 1) * 1024 + qg];
    f32x16 s0, s1;
#pragma unroll
    for (int r = 0; r < 16; ++r) { s0[r] = rh0 + rw[r]; s1[r] = rh1 + rw[r]; }
#pragma unroll
    for (int c = 0; c < 4; ++c) {
      s0 = __builtin_amdgcn_mfma_f32_32x32x16_bf16(kf[cur][c], qf[c], s0, 0, 0, 0);
      s1 = __builtin_amdgcn_mfma_f32_32x32x16_bf16(kf[cur][4 + c], qf[c], s1, 0, 0, 0);
    }
    // |S'| <= ~4.5 -> exp2 without max-subtract (log2e folded upstream)
#pragma unroll
    for (int r = 0; r < 16; ++r) { s0[r] = exp2f(s0[r]); s1[r] = exp2f(s1[r]); }
#pragma unroll
    for (int r = 0; r < 16; ++r) lsum += s0[r] + s1[r];
    // HW pack to bf16 + permlane half-exchange -> PV A-fragments (T12)
    unsigned int pw[16];
#pragma unroll
    for (int j = 0; j < 8; ++j) pw[j] = cvtpk(s0[2 * j], s0[2 * j + 1]);
#pragma unroll
    for (int j = 0; j < 8; ++j) pw[8 + j] = cvtpk(s1[2 * j], s1[2 * j + 1]);
    plswap(pw[0], pw[2]);  plswap(pw[1], pw[3]);
    plswap(pw[4], pw[6]);  plswap(pw[5], pw[7]);
    plswap(pw[8], pw[10]); plswap(pw[9], pw[11]);
    plswap(pw[12], pw[14]); plswap(pw[13], pw[15]);
#pragma unroll
    for (int cc = 0; cc < 4; ++cc) {
      uint4v w4 = {pw[cc * 4 + 0], pw[cc * 4 + 1], pw[cc * 4 + 2], pw[cc * 4 + 3]};
      short8 pa = __builtin_bit_cast(short8, w4);
      o0 = __builtin_amdgcn_mfma_f32_32x32x16_bf16(pa, vb0[cc], o0, 0, 0, 0);
      o1 = __builtin_amdgcn_mfma_f32_32x32x16_bf16(pa, vb1[cc], o1, 0, 0, 0);
    }
  }
  lsum += __shfl_xor(lsum, 32, 64);
  if (hi == 0) lsums[wq][wk][lq] = lsum;
  // store the O-half this wave will NOT finalize (wk==0 finalizes d<32 -> stores o1)
#pragma unroll
  for (int r = 0; r < 16; ++r)
    part[wq][wk][lane][r] = wk ? o0[r] : o1[r];
  __syncthreads();
  const int b = bh / 12, head = bh - b * 12;
  u16* outp = aout + (size_t)b * 1024 * 768 + head * 64 + wk * 32;
#pragma unroll
  for (int r = 0; r < 16; ++r) {
    const int qr = (r & 3) + 8 * (r >> 2) + 4 * hi;
    const float inv = 1.0f / (lsums[wq][0][qr] + lsums[wq][1][qr]);
    const float own = wk ? o1[r] : o0[r];
    const float val = own + part[wq][wk ^ 1][lane][r];
    outp[(size_t)(q0 + qr) * 768 + lq] = f2bf(val * inv);
  }
}

// ---------------- launch ----------------
extern "C" void kernel_launch(void* const* d_in, const int* in_sizes, int n_in,
                              void* d_out, int out_size, void* d_ws, size_t ws_size,
                              hipStream_t stream) {
  const float* x = (const float*)d_in[0];
  const float* qkv_w = (const float*)d_in[1];
  const float* qkv_b = (const float*)d_in[2];
  const float* proj_w = (const float*)d_in[3];
  const float* proj_b = (const float*)d_in[4];
  const float* rph = (const float*)d_in[5];
  const float* rpw = (const float*)d_in[6];
  float* out = (float*)d_out;
  char* ws = (char*)d_ws;
  u16* xb     = (u16*)(ws + 0);
  u16* wqkv   = (u16*)(ws + 6291456);
  u16* wproj  = (u16*)(ws + 9830400);
  u16* pq     = (u16*)(ws + 11010048);
  u16* pk     = (u16*)(ws + 17301504);
  u16* pv     = (u16*)(ws + 23592960);
  float* rhp  = (float*)(ws + 29884416);
  float* rwp  = (float*)(ws + 36175872);
  u16* aout   = (u16*)(ws + 42467328);
  u16* rphb   = (u16*)(ws + 48758784);
  u16* rpwb   = (u16*)(ws + 48766848);

  cvt_all<<<1024, 256, 0, stream>>>(x, xb, 3145728, qkv_w, wqkv, 1769472,
                                    proj_w, wproj, 589824, rph, rphb, 4032,
                                    rpw, rpwb, 4032);
  gemm128<0><<<dim3(18, 32), 256, 0, stream>>>(xb, wqkv, qkv_b, pq, pk, pv,
                                               nullptr, 4096, 2304, 768);
  rel_kernel<<<dim3(48, 32, 2), 64, 0, stream>>>(pq, rphb, rpwb, rhp, rwp);
  attn_kernel<<<dim3(48, 16), 256, 0, stream>>>(pq, pk, pv, rhp, rwp, aout);
  gemm128<1><<<dim3(6, 32), 256, 0, stream>>>(aout, wproj, proj_b, nullptr, nullptr,
                                              nullptr, out, 4096, 768, 768);
}

// Round 13
// 87.988 us; speedup vs baseline: 2.2393x; 1.0163x over previous
//
#include <hip/hip_runtime.h>
#include <stdint.h>

typedef unsigned short u16;
typedef __attribute__((ext_vector_type(8))) short short8;
typedef __attribute__((ext_vector_type(8))) u16 ushort8;
typedef __attribute__((ext_vector_type(4))) float f32x4;
typedef __attribute__((ext_vector_type(16))) float f32x16;
typedef __attribute__((ext_vector_type(4))) unsigned int uint4v;

#define LOG2E 1.44269504088896f

__device__ __forceinline__ u16 f2bf(float f) {
  unsigned int u = __builtin_bit_cast(unsigned int, f);
  u += 0x7FFF + ((u >> 16) & 1);  // RNE; inputs finite
  return (u16)(u >> 16);
}
// HW packed f32->bf16 (RNE): lo = a, hi = b.
__device__ __forceinline__ unsigned int cvtpk(float a, float b) {
  unsigned int r;
  asm("v_cvt_pk_bf16_f32 %0, %1, %2" : "=v"(r) : "v"(a), "v"(b));
  return r;
}
// v_permlane32_swap_b32: a.hi32lanes <-> b.lo32lanes.
__device__ __forceinline__ void plswap(unsigned int& a, unsigned int& b) {
  asm("v_permlane32_swap_b32 %0, %1" : "+v"(a), "+v"(b));
}
__device__ __forceinline__ void gload_lds16(const u16* g, u16* l) {
  __builtin_amdgcn_global_load_lds((const __attribute__((address_space(1))) void*)g,
                                   (__attribute__((address_space(3))) void*)l, 16, 0, 0);
}

// ---------------- fused fp32 -> bf16 convert (all 5 tensors, 1 launch) ----------
__global__ __launch_bounds__(256) void cvt_all(
    const float* __restrict__ s0, u16* __restrict__ d0, int n0,
    const float* __restrict__ s1, u16* __restrict__ d1, int n1,
    const float* __restrict__ s2, u16* __restrict__ d2, int n2,
    const float* __restrict__ s3, u16* __restrict__ d3, int n3,
    const float* __restrict__ s4, u16* __restrict__ d4, int n4) {
  const int tid0 = blockIdx.x * 256 + threadIdx.x;
  const int stride = gridDim.x * 256 * 4;
#define CVT_SEG(S, D, N)                                       \
  for (int i = tid0 * 4; i < (N); i += stride) {               \
    float4 v = *(const float4*)((S) + i);                      \
    *(uint2*)((D) + i) = make_uint2(cvtpk(v.x, v.y), cvtpk(v.z, v.w)); \
  }
  CVT_SEG(s0, d0, n0)
  CVT_SEG(s1, d1, n1)
  CVT_SEG(s2, d2, n2)
  CVT_SEG(s3, d3, n3)
  CVT_SEG(s4, d4, n4)
#undef CVT_SEG
}

// ---------------- 128x128 bf16 GEMM, C = A * B^T (+bias) ----------------
// 2-PHASE double-buffered K-loop (T3-minimum); LDS XOR-swizzled (T2).
// XCD-aware block swizzle (T1): nwg%8==0 for both launches; each XCD gets a
// contiguous chunk (4 bm-rows x all bn) whose B-panel+A-panel fit its 4MB L2.
// MODE 0: qkv epilogue -> FRAGMENT-MAJOR packed q/k/v (q pre-scaled by
//         0.125*log2e so attention uses exp2). MODE 1: proj -> fp32 out.
#define CTS 130  // ct row stride (u16): bank step 65 == 1 mod 32
template <int MODE>
__global__ __launch_bounds__(256) void gemm128(
    const u16* __restrict__ A, const u16* __restrict__ B,
    const float* __restrict__ bias,
    u16* __restrict__ qo, u16* __restrict__ ko, u16* __restrict__ vto,
    float* __restrict__ fout, int M, int N, int K) {
  __shared__ u16 smem[4 * 128 * 64];  // [2 dbuf][A,B] 64 KB; epilogue reuses as ct
  const int tid = threadIdx.x;
  const int lane = tid & 63, wave = tid >> 6;
  const int wr = wave >> 1, wc = wave & 1;
  const int l15 = lane & 15, l4 = lane >> 4;
  // XCD swizzle: fid%8 == XCD; give each XCD a contiguous logical chunk.
  const int fid = blockIdx.y * gridDim.x + blockIdx.x;
  const int cpx = (gridDim.x * gridDim.y) >> 3;  // nwg % 8 == 0 for our grids
  const int swz = (fid & 7) * cpx + (fid >> 3);
  const int bxs = swz % gridDim.x, bys = swz / gridDim.x;
  const int bm = bys << 7, bn = bxs << 7;
  f32x4 acc[4][4] = {};
  const int nkt = K >> 6;

#define STAGE(buf, kt)                                                        \
  {                                                                           \
    u16* As_ = smem + (buf) * 16384;                                          \
    u16* Bs_ = As_ + 8192;                                                    \
    const int k0_ = (kt) << 6;                                                \
    _Pragma("unroll") for (int j = 0; j < 4; ++j) {                           \
      const int cbase = j * 256 + wave * 64;                                  \
      const int chunk = cbase + lane;                                         \
      const int row = chunk >> 3;                                             \
      const int co = (((chunk & 7) ^ (row & 7)) << 3);                        \
      gload_lds16(A + (size_t)(bm + row) * K + k0_ + co, As_ + cbase * 8);    \
      gload_lds16(B + (size_t)(bn + row) * K + k0_ + co, Bs_ + cbase * 8);    \
    }                                                                         \
  }

  STAGE(0, 0)
  __syncthreads();  // vmcnt(0) drain: buf0 ready
  int cur = 0;
  for (int kt = 0; kt < nkt; ++kt) {
    if (kt + 1 < nkt) STAGE(cur ^ 1, kt + 1)  // prefetch next tile
    const u16* As = smem + cur * 16384;
    const u16* Bs = As + 8192;
    short8 af[2][4], bf[2][4];
#pragma unroll
    for (int kc = 0; kc < 2; ++kc)
#pragma unroll
      for (int i = 0; i < 4; ++i) {
        const int rA = wr * 64 + i * 16 + l15;
        const int rB = wc * 64 + i * 16 + l15;
        af[kc][i] = *(const short8*)((const char*)As +
            (((rA * 64 + kc * 32 + l4 * 8) * 2) ^ ((rA & 7) << 4)));
        bf[kc][i] = *(const short8*)((const char*)Bs +
            (((rB * 64 + kc * 32 + l4 * 8) * 2) ^ ((rB & 7) << 4)));
      }
#pragma unroll
    for (int kc = 0; kc < 2; ++kc)
#pragma unroll
      for (int mi = 0; mi < 4; ++mi)
#pragma unroll
        for (int ni = 0; ni < 4; ++ni)
          acc[mi][ni] = __builtin_amdgcn_mfma_f32_16x16x32_bf16(
              af[kc][mi], bf[kc][ni], acc[mi][ni], 0, 0, 0);
    __syncthreads();  // drains prefetch (vmcnt 0) + all reads of cur done
    cur ^= 1;
  }
#undef STAGE

  if (MODE == 1) {
#pragma unroll
    for (int ni = 0; ni < 4; ++ni) {
      const int col = wc * 64 + ni * 16 + l15;
      const float bv = bias[bn + col];
#pragma unroll
      for (int mi = 0; mi < 4; ++mi)
#pragma unroll
        for (int j = 0; j < 4; ++j) {
          const int row = wr * 64 + mi * 16 + l4 * 4 + j;
          fout[(size_t)(bm + row) * N + bn + col] = acc[mi][ni][j] + bv;
        }
    }
    return;
  }
  // MODE 0: stage C tile to LDS as bf16, then scatter to packed layouts
  u16* ct = smem;  // [128][CTS]  (loop ended with a barrier)
  const int which = bn / 768;  // 0:q 1:k 2:v (768 = 6*128, boundaries align)
  const float sc = (which == 0) ? 0.125f * LOG2E : 1.0f;  // SDPA scale + log2e fold
#pragma unroll
  for (int ni = 0; ni < 4; ++ni) {
    const int col = wc * 64 + ni * 16 + l15;
    const float bv = bias[bn + col];
#pragma unroll
    for (int mi = 0; mi < 4; ++mi)
#pragma unroll
      for (int j = 0; j < 4; ++j) {
        const int row = wr * 64 + mi * 16 + l4 * 4 + j;
        ct[row * CTS + col] = f2bf((acc[mi][ni][j] + bv) * sc);
      }
  }
  __syncthreads();
  const int nrel = bn - which * 768;
  const int head0 = nrel >> 6;  // 128-wide tile covers exactly 2 heads
  const int b = bm >> 10;       // 128-row tile stays inside one batch
  if (which < 2) {
    u16* dst0 = which ? ko : qo;
    const int row = tid >> 1, hp = tid & 1;  // hp selects head parity
    const int head = head0 + hp;
    const int pos = (bm + row) & 1023;
    const u16* s = ct + row * CTS + hp * 64;
    u16* base = dst0 + ((size_t)(b * 12 + head)) * 65536;
    if (which == 0) {
      const int qsub = pos >> 5, lq = pos & 31;
#pragma unroll
      for (int g = 0; g < 8; ++g) {
        const int c = g >> 1, hi = g & 1;
        *(ushort8*)(base + ((qsub * 4 + c) * 64 + hi * 32 + lq) * 8) =
            *(const ushort8*)(s + g * 8);
      }
    } else {
      const int t = pos >> 6, hf = (pos >> 5) & 1, lq = pos & 31;
#pragma unroll
      for (int g = 0; g < 8; ++g) {
        const int c = g >> 1, hi = g & 1;
        *(ushort8*)(base + (((t * 4 + c) * 2 + hf) * 64 + hi * 32 + lq) * 8) =
            *(const ushort8*)(s + g * 8);
      }
    }
  } else {
    const int c = tid >> 1, seg = tid & 1;
    const int head = head0 + (c >> 6), dd = c & 63;
    const int posbase = (bm & 1023) + seg * 64;
    const int t = posbase >> 6;
    const int half = dd >> 5, lqd = dd & 31;
    u16* base = vto + ((size_t)(b * 12 + head)) * 65536;
    const u16* s = ct + (seg * 64) * CTS + c;
#pragma unroll
    for (int g = 0; g < 8; ++g) {
      ushort8 o;
#pragma unroll
      for (int e = 0; e < 8; ++e) o[e] = s[(g * 8 + e) * CTS];
      *(ushort8*)(base + (((t * 4 + (g >> 1)) * 2 + half) * 64 + (g & 1) * 32 + lqd) * 8) = o;
    }
  }
}

// ---------------- rel_h / rel_w via MFMA ----------------
// q is pre-scaled by 0.125*log2e; the x8 here yields log2e * bias exactly.
// Outputs PACKED: RH_p[bh][kh32][q1024], RW_p[bh][w32][q1024]
__global__ __launch_bounds__(64) void rel_kernel(
    const u16* __restrict__ pq, const u16* __restrict__ th,
    const u16* __restrict__ tw, float* __restrict__ rhp, float* __restrict__ rwp) {
  const int bh = blockIdx.x, h = blockIdx.y, type = blockIdx.z;
  const int lane = threadIdx.x & 63, lq = lane & 31, hi = lane >> 5;
  short8 qf[4];
#pragma unroll
  for (int c = 0; c < 4; ++c)
    qf[c] = *(const short8*)(pq + (size_t)bh * 65536 + ((h * 4 + c) * 64 + lane) * 8);
  if (type == 0) {
    const int tr = h - lq + 31;  // in [0,62]; bias key-h index kh == lq
    f32x16 acc{};
#pragma unroll
    for (int c = 0; c < 4; ++c) {
      short8 bfr = *(const short8*)(th + tr * 64 + c * 16 + hi * 8);
      acc = __builtin_amdgcn_mfma_f32_32x32x16_bf16(qf[c], bfr, acc, 0, 0, 0);
    }
    float* O = rhp + (size_t)bh * 32768 + lq * 1024 + h * 32;
#pragma unroll
    for (int r = 0; r < 16; ++r) {
      const int w = (r & 3) + 8 * (r >> 2) + 4 * hi;  // q-row within h-block
      O[w] = acc[r] * 8.0f;
    }
  } else {
    const int r0 = lq;                          // j = lq
    const int r1 = (lq == 31) ? 62 : (32 + lq); // j = 32+lq (clamped; lq==31 unused)
    f32x16 a0{}, a1{};
#pragma unroll
    for (int c = 0; c < 4; ++c) {
      short8 b0 = *(const short8*)(tw + r0 * 64 + c * 16 + hi * 8);
      short8 b1 = *(const short8*)(tw + r1 * 64 + c * 16 + hi * 8);
      a0 = __builtin_amdgcn_mfma_f32_32x32x16_bf16(qf[c], b0, a0, 0, 0, 0);
      a1 = __builtin_amdgcn_mfma_f32_32x32x16_bf16(qf[c], b1, a1, 0, 0, 0);
    }
    float* O = rwp + (size_t)bh * 32768 + h * 32;
#pragma unroll
    for (int r = 0; r < 16; ++r) {
      const int w = (r & 3) + 8 * (r >> 2) + 4 * hi;
      const int k0i = w - lq + 31;  // from tile j=lq
      const int k1i = w - lq - 1;   // from tile j=32+lq
      if (k0i >= 0 && k0i < 32) O[k0i * 1024 + w] = a0[r] * 8.0f;
      if (k1i >= 0) O[k1i * 1024 + w] = a1[r] * 8.0f;
    }
  }
}

// ---------------- fused attention, 2-way split-K + K-register-prefetch ----------
// grid (48 bh, 16 qtiles64), 256 threads = 4 waves = (2 q-subtiles x 2 key-halves).
// K fragments prefetched one full tile ahead (R12, proven). NEW: QK MFMAs start
// from ZERO C-init (no wait on bias); bias = rh+rw is computed WHILE the MFMA
// chain runs (rh loads issued at iteration top) and folded in at the exp stage:
// exp2(s + rh + rw). Removes the rh L2/L3 latency (~300-600cy/tile) from the
// critical chain. No swizzle on this grid: all 16 qt-blocks of a head already
// land on one XCD (48%8==0), giving K/V L2 locality for free.
__global__ __launch_bounds__(256) void attn_kernel(
    const u16* __restrict__ pq, const u16* __restrict__ pk,
    const u16* __restrict__ pv, const float* __restrict__ rhp,
    const float* __restrict__ rwp, u16* __restrict__ aout) {
  const int bh = blockIdx.x, qt = blockIdx.y;
  const int tid = threadIdx.x, lane = tid & 63, wave = tid >> 6;
  const int wq = wave >> 1, wk = wave & 1;
  const int lq = lane & 31, hi = lane >> 5;
  const int q0 = qt * 64 + wq * 32;
  const u16* Qb = pq + (size_t)bh * 65536;
  const u16* Kb = pk + (size_t)bh * 65536;
  const u16* Vb = pv + (size_t)bh * 65536;
  const float* RH = rhp + (size_t)bh * 32768;
  const float* RW = rwp + (size_t)bh * 32768;
  __shared__ float part[2][2][64][17];  // [wq][wk][lane][r], stride-17 pad
  __shared__ float lsums[2][2][32];
  const int qg = q0 + lq;  // this lane's q row
  const int qsub = qt * 2 + wq;
  short8 qf[4];
#pragma unroll
  for (int c = 0; c < 4; ++c)
    qf[c] = *(const short8*)(Qb + ((qsub * 4 + c) * 64 + lane) * 8);
  float rw[16];
#pragma unroll
  for (int r = 0; r < 16; ++r)
    rw[r] = RW[((r & 3) + 8 * (r >> 2) + 4 * hi) * 1024 + qg];
  f32x16 o0{}, o1{};
  float lsum = 0.f;
  short8 kf[2][8];  // [tile parity][half*4 + c] prefetched K fragments
  {
    const int t0 = wk * 8;
#pragma unroll
    for (int c = 0; c < 4; ++c) {
      kf[0][c]     = *(const short8*)(Kb + (((t0 * 4 + c) * 2 + 0) * 64 + lane) * 8);
      kf[0][4 + c] = *(const short8*)(Kb + (((t0 * 4 + c) * 2 + 1) * 64 + lane) * 8);
    }
  }
#pragma unroll
  for (int t = 0; t < 8; ++t) {
    const int tt = wk * 8 + t;
    const int cur = t & 1, nxt = cur ^ 1;
    // rh loads issued at top; consumed only after the QK MFMA chain
    const float rh0 = RH[(tt * 2) * 1024 + qg];
    const float rh1 = RH[(tt * 2 + 1) * 1024 + qg];
    // prefetch next tile's K (consumed one full iteration later)
    if (t < 7) {
      const int tn = tt + 1;
#pragma unroll
      for (int c = 0; c < 4; ++c) {
        kf[nxt][c]     = *(const short8*)(Kb + (((tn * 4 + c) * 2 + 0) * 64 + lane) * 8);
        kf[nxt][4 + c] = *(const short8*)(Kb + (((tn * 4 + c) * 2 + 1) * 64 + lane) * 8);
      }
    }
    // V loads issued early within the iteration: hidden under QK^T + exp
    short8 vb0[4], vb1[4];
#pragma unroll
    for (int cc = 0; cc < 4; ++cc) {
      vb0[cc] = *(const short8*)(Vb + (((tt * 4 + cc) * 2 + 0) * 64 + lane) * 8);
      vb1[cc] = *(const short8*)(Vb + (((tt * 4 + cc) * 2 + 1) * 64 + lane) * 8);
    }
    // QK^T from zero C-init: K is in registers (prefetched) -> no wait
    f32x16 s0{}, s1{};
#pragma unroll
    for (int c = 0; c < 4; ++c) {
      s0 = __builtin_amdgcn_mfma_f32_32x32x16_bf16(kf[cur][c], qf[c], s0, 0, 0, 0);
      s1 = __builtin_amdgcn_mfma_f32_32x32x16_bf16(kf[cur][4 + c], qf[c], s1, 0, 0, 0);
    }
    // bias computed while MFMAs are in flight (depends only on rh + regs)
    float b0[16], b1[16];
#pragma unroll
    for (int r = 0; r < 16; ++r) { b0[r] = rh0 + rw[r]; b1[r] = rh1 + rw[r]; }
    // |S'| <= ~4.5 -> exp2 without max-subtract (log2e folded upstream)
#pragma unroll
    for (int r = 0; r < 16; ++r) {
      s0[r] = exp2f(s0[r] + b0[r]);
      s1[r] = exp2f(s1[r] + b1[r]);
    }
#pragma unroll
    for (int r = 0; r < 16; ++r) lsum += s0[r] + s1[r];
    // HW pack to bf16 + permlane half-exchange -> PV A-fragments (T12)
    unsigned int pw[16];
#pragma unroll
    for (int j = 0; j < 8; ++j) pw[j] = cvtpk(s0[2 * j], s0[2 * j + 1]);
#pragma unroll
    for (int j = 0; j < 8; ++j) pw[8 + j] = cvtpk(s1[2 * j], s1[2 * j + 1]);
    plswap(pw[0], pw[2]);  plswap(pw[1], pw[3]);
    plswap(pw[4], pw[6]);  plswap(pw[5], pw[7]);
    plswap(pw[8], pw[10]); plswap(pw[9], pw[11]);
    plswap(pw[12], pw[14]); plswap(pw[13], pw[15]);
#pragma unroll
    for (int cc = 0; cc < 4; ++cc) {
      uint4v w4 = {pw[cc * 4 + 0], pw[cc * 4 + 1], pw[cc * 4 + 2], pw[cc * 4 + 3]};
      short8 pa = __builtin_bit_cast(short8, w4);
      o0 = __builtin_amdgcn_mfma_f32_32x32x16_bf16(pa, vb0[cc], o0, 0, 0, 0);
      o1 = __builtin_amdgcn_mfma_f32_32x32x16_bf16(pa, vb1[cc], o1, 0, 0, 0);
    }
  }
  lsum += __shfl_xor(lsum, 32, 64);
  if (hi == 0) lsums[wq][wk][lq] = lsum;
  // store the O-half this wave will NOT finalize (wk==0 finalizes d<32 -> stores o1)
#pragma unroll
  for (int r = 0; r < 16; ++r)
    part[wq][wk][lane][r] = wk ? o0[r] : o1[r];
  __syncthreads();
  const int b = bh / 12, head = bh - b * 12;
  u16* outp = aout + (size_t)b * 1024 * 768 + head * 64 + wk * 32;
#pragma unroll
  for (int r = 0; r < 16; ++r) {
    const int qr = (r & 3) + 8 * (r >> 2) + 4 * hi;
    const float inv = 1.0f / (lsums[wq][0][qr] + lsums[wq][1][qr]);
    const float own = wk ? o1[r] : o0[r];
    const float val = own + part[wq][wk ^ 1][lane][r];
    outp[(size_t)(q0 + qr) * 768 + lq] = f2bf(val * inv);
  }
}

// ---------------- launch ----------------
extern "C" void kernel_launch(void* const* d_in, const int* in_sizes, int n_in,
                              void* d_out, int out_size, void* d_ws, size_t ws_size,
                              hipStream_t stream) {
  const float* x = (const float*)d_in[0];
  const float* qkv_w = (const float*)d_in[1];
  const float* qkv_b = (const float*)d_in[2];
  const float* proj_w = (const float*)d_in[3];
  const float* proj_b = (const float*)d_in[4];
  const float* rph = (const float*)d_in[5];
  const float* rpw = (const float*)d_in[6];
  float* out = (float*)d_out;
  char* ws = (char*)d_ws;
  u16* xb     = (u16*)(ws + 0);
  u16* wqkv   = (u16*)(ws + 6291456);
  u16* wproj  = (u16*)(ws + 9830400);
  u16* pq     = (u16*)(ws + 11010048);
  u16* pk     = (u16*)(ws + 17301504);
  u16* pv     = (u16*)(ws + 23592960);
  float* rhp  = (float*)(ws + 29884416);
  float* rwp  = (float*)(ws + 36175872);
  u16* aout   = (u16*)(ws + 42467328);
  u16* rphb   = (u16*)(ws + 48758784);
  u16* rpwb   = (u16*)(ws + 48766848);

  cvt_all<<<1024, 256, 0, stream>>>(x, xb, 3145728, qkv_w, wqkv, 1769472,
                                    proj_w, wproj, 589824, rph, rphb, 4032,
                                    rpw, rpwb, 4032);
  gemm128<0><<<dim3(18, 32), 256, 0, stream>>>(xb, wqkv, qkv_b, pq, pk, pv,
                                               nullptr, 4096, 2304, 768);
  rel_kernel<<<dim3(48, 32, 2), 64, 0, stream>>>(pq, rphb, rpwb, rhp, rwp);
  attn_kernel<<<dim3(48, 16), 256, 0, stream>>>(pq, pk, pv, rhp, rwp, aout);
  gemm128<1><<<dim3(6, 32), 256, 0, stream>>>(aout, wproj, proj_b, nullptr, nullptr,
                                              nullptr, out, 4096, 768, 768);
}

// Round 14
// 87.549 us; speedup vs baseline: 2.2505x; 1.0050x over previous
//
#include <hip/hip_runtime.h>
#include <stdint.h>

typedef unsigned short u16;
typedef __attribute__((ext_vector_type(8))) short short8;
typedef __attribute__((ext_vector_type(8))) u16 ushort8;
typedef __attribute__((ext_vector_type(4))) float f32x4;
typedef __attribute__((ext_vector_type(16))) float f32x16;
typedef __attribute__((ext_vector_type(4))) unsigned int uint4v;

#define LOG2E 1.44269504088896f

__device__ __forceinline__ u16 f2bf(float f) {
  unsigned int u = __builtin_bit_cast(unsigned int, f);
  u += 0x7FFF + ((u >> 16) & 1);  // RNE; inputs finite
  return (u16)(u >> 16);
}
// HW packed f32->bf16 (RNE): lo = a, hi = b.
__device__ __forceinline__ unsigned int cvtpk(float a, float b) {
  unsigned int r;
  asm("v_cvt_pk_bf16_f32 %0, %1, %2" : "=v"(r) : "v"(a), "v"(b));
  return r;
}
// v_permlane32_swap_b32: a.hi32lanes <-> b.lo32lanes.
__device__ __forceinline__ void plswap(unsigned int& a, unsigned int& b) {
  asm("v_permlane32_swap_b32 %0, %1" : "+v"(a), "+v"(b));
}
__device__ __forceinline__ void gload_lds16(const u16* g, u16* l) {
  __builtin_amdgcn_global_load_lds((const __attribute__((address_space(1))) void*)g,
                                   (__attribute__((address_space(3))) void*)l, 16, 0, 0);
}

// ---------------- fused fp32 -> bf16 convert (all 5 tensors, 1 launch) ----------
__global__ __launch_bounds__(256) void cvt_all(
    const float* __restrict__ s0, u16* __restrict__ d0, int n0,
    const float* __restrict__ s1, u16* __restrict__ d1, int n1,
    const float* __restrict__ s2, u16* __restrict__ d2, int n2,
    const float* __restrict__ s3, u16* __restrict__ d3, int n3,
    const float* __restrict__ s4, u16* __restrict__ d4, int n4) {
  const int tid0 = blockIdx.x * 256 + threadIdx.x;
  const int stride = gridDim.x * 256 * 4;
#define CVT_SEG(S, D, N)                                       \
  for (int i = tid0 * 4; i < (N); i += stride) {               \
    float4 v = *(const float4*)((S) + i);                      \
    *(uint2*)((D) + i) = make_uint2(cvtpk(v.x, v.y), cvtpk(v.z, v.w)); \
  }
  CVT_SEG(s0, d0, n0)
  CVT_SEG(s1, d1, n1)
  CVT_SEG(s2, d2, n2)
  CVT_SEG(s3, d3, n3)
  CVT_SEG(s4, d4, n4)
#undef CVT_SEG
}

// ---------------- 128x128 bf16 GEMM, C = A * B^T (+bias) ----------------
// 2-PHASE double-buffered K-loop (T3-minimum); LDS XOR-swizzled (T2).
// XCD-aware block swizzle (T1): nwg%8==0 for both launches.
// MODE 0: qkv epilogue -> FRAGMENT-MAJOR packed q/k/v (q pre-scaled by
//         0.125*log2e so attention uses exp2). MODE 1: proj -> fp32 out.
#define CTS 130  // ct row stride (u16): bank step 65 == 1 mod 32
template <int MODE>
__global__ __launch_bounds__(256) void gemm128(
    const u16* __restrict__ A, const u16* __restrict__ B,
    const float* __restrict__ bias,
    u16* __restrict__ qo, u16* __restrict__ ko, u16* __restrict__ vto,
    float* __restrict__ fout, int M, int N, int K) {
  __shared__ u16 smem[4 * 128 * 64];  // [2 dbuf][A,B] 64 KB; epilogue reuses as ct
  const int tid = threadIdx.x;
  const int lane = tid & 63, wave = tid >> 6;
  const int wr = wave >> 1, wc = wave & 1;
  const int l15 = lane & 15, l4 = lane >> 4;
  // XCD swizzle: fid%8 == XCD; give each XCD a contiguous logical chunk.
  const int fid = blockIdx.y * gridDim.x + blockIdx.x;
  const int cpx = (gridDim.x * gridDim.y) >> 3;  // nwg % 8 == 0 for our grids
  const int swz = (fid & 7) * cpx + (fid >> 3);
  const int bxs = swz % gridDim.x, bys = swz / gridDim.x;
  const int bm = bys << 7, bn = bxs << 7;
  f32x4 acc[4][4] = {};
  const int nkt = K >> 6;

#define STAGE(buf, kt)                                                        \
  {                                                                           \
    u16* As_ = smem + (buf) * 16384;                                          \
    u16* Bs_ = As_ + 8192;                                                    \
    const int k0_ = (kt) << 6;                                                \
    _Pragma("unroll") for (int j = 0; j < 4; ++j) {                           \
      const int cbase = j * 256 + wave * 64;                                  \
      const int chunk = cbase + lane;                                         \
      const int row = chunk >> 3;                                             \
      const int co = (((chunk & 7) ^ (row & 7)) << 3);                        \
      gload_lds16(A + (size_t)(bm + row) * K + k0_ + co, As_ + cbase * 8);    \
      gload_lds16(B + (size_t)(bn + row) * K + k0_ + co, Bs_ + cbase * 8);    \
    }                                                                         \
  }

  STAGE(0, 0)
  __syncthreads();  // vmcnt(0) drain: buf0 ready
  int cur = 0;
  for (int kt = 0; kt < nkt; ++kt) {
    if (kt + 1 < nkt) STAGE(cur ^ 1, kt + 1)  // prefetch next tile
    const u16* As = smem + cur * 16384;
    const u16* Bs = As + 8192;
    short8 af[2][4], bf[2][4];
#pragma unroll
    for (int kc = 0; kc < 2; ++kc)
#pragma unroll
      for (int i = 0; i < 4; ++i) {
        const int rA = wr * 64 + i * 16 + l15;
        const int rB = wc * 64 + i * 16 + l15;
        af[kc][i] = *(const short8*)((const char*)As +
            (((rA * 64 + kc * 32 + l4 * 8) * 2) ^ ((rA & 7) << 4)));
        bf[kc][i] = *(const short8*)((const char*)Bs +
            (((rB * 64 + kc * 32 + l4 * 8) * 2) ^ ((rB & 7) << 4)));
      }
#pragma unroll
    for (int kc = 0; kc < 2; ++kc)
#pragma unroll
      for (int mi = 0; mi < 4; ++mi)
#pragma unroll
        for (int ni = 0; ni < 4; ++ni)
          acc[mi][ni] = __builtin_amdgcn_mfma_f32_16x16x32_bf16(
              af[kc][mi], bf[kc][ni], acc[mi][ni], 0, 0, 0);
    __syncthreads();  // drains prefetch (vmcnt 0) + all reads of cur done
    cur ^= 1;
  }
#undef STAGE

  if (MODE == 1) {
#pragma unroll
    for (int ni = 0; ni < 4; ++ni) {
      const int col = wc * 64 + ni * 16 + l15;
      const float bv = bias[bn + col];
#pragma unroll
      for (int mi = 0; mi < 4; ++mi)
#pragma unroll
        for (int j = 0; j < 4; ++j) {
          const int row = wr * 64 + mi * 16 + l4 * 4 + j;
          fout[(size_t)(bm + row) * N + bn + col] = acc[mi][ni][j] + bv;
        }
    }
    return;
  }
  // MODE 0: stage C tile to LDS as bf16, then scatter to packed layouts
  u16* ct = smem;  // [128][CTS]  (loop ended with a barrier)
  const int which = bn / 768;  // 0:q 1:k 2:v (768 = 6*128, boundaries align)
  const float sc = (which == 0) ? 0.125f * LOG2E : 1.0f;  // SDPA scale + log2e fold
#pragma unroll
  for (int ni = 0; ni < 4; ++ni) {
    const int col = wc * 64 + ni * 16 + l15;
    const float bv = bias[bn + col];
#pragma unroll
    for (int mi = 0; mi < 4; ++mi)
#pragma unroll
      for (int j = 0; j < 4; ++j) {
        const int row = wr * 64 + mi * 16 + l4 * 4 + j;
        ct[row * CTS + col] = f2bf((acc[mi][ni][j] + bv) * sc);
      }
  }
  __syncthreads();
  const int nrel = bn - which * 768;
  const int head0 = nrel >> 6;  // 128-wide tile covers exactly 2 heads
  const int b = bm >> 10;       // 128-row tile stays inside one batch
  if (which < 2) {
    u16* dst0 = which ? ko : qo;
    const int row = tid >> 1, hp = tid & 1;  // hp selects head parity
    const int head = head0 + hp;
    const int pos = (bm + row) & 1023;
    const u16* s = ct + row * CTS + hp * 64;
    u16* base = dst0 + ((size_t)(b * 12 + head)) * 65536;
    if (which == 0) {
      const int qsub = pos >> 5, lq = pos & 31;
#pragma unroll
      for (int g = 0; g < 8; ++g) {
        const int c = g >> 1, hi = g & 1;
        *(ushort8*)(base + ((qsub * 4 + c) * 64 + hi * 32 + lq) * 8) =
            *(const ushort8*)(s + g * 8);
      }
    } else {
      const int t = pos >> 6, hf = (pos >> 5) & 1, lq = pos & 31;
#pragma unroll
      for (int g = 0; g < 8; ++g) {
        const int c = g >> 1, hi = g & 1;
        *(ushort8*)(base + (((t * 4 + c) * 2 + hf) * 64 + hi * 32 + lq) * 8) =
            *(const ushort8*)(s + g * 8);
      }
    }
  } else {
    const int c = tid >> 1, seg = tid & 1;
    const int head = head0 + (c >> 6), dd = c & 63;
    const int posbase = (bm & 1023) + seg * 64;
    const int t = posbase >> 6;
    const int half = dd >> 5, lqd = dd & 31;
    u16* base = vto + ((size_t)(b * 12 + head)) * 65536;
    const u16* s = ct + (seg * 64) * CTS + c;
#pragma unroll
    for (int g = 0; g < 8; ++g) {
      ushort8 o;
#pragma unroll
      for (int e = 0; e < 8; ++e) o[e] = s[(g * 8 + e) * CTS];
      *(ushort8*)(base + (((t * 4 + (g >> 1)) * 2 + half) * 64 + (g & 1) * 32 + lqd) * 8) = o;
    }
  }
}

// ---------------- rel_h / rel_w via MFMA ----------------
// q is pre-scaled by 0.125*log2e; the x8 here yields log2e * bias exactly.
// Outputs PACKED: RH_p[bh][kh32][q1024], RW_p[bh][w32][q1024]
__global__ __launch_bounds__(64) void rel_kernel(
    const u16* __restrict__ pq, const u16* __restrict__ th,
    const u16* __restrict__ tw, float* __restrict__ rhp, float* __restrict__ rwp) {
  const int bh = blockIdx.x, h = blockIdx.y, type = blockIdx.z;
  const int lane = threadIdx.x & 63, lq = lane & 31, hi = lane >> 5;
  short8 qf[4];
#pragma unroll
  for (int c = 0; c < 4; ++c)
    qf[c] = *(const short8*)(pq + (size_t)bh * 65536 + ((h * 4 + c) * 64 + lane) * 8);
  if (type == 0) {
    const int tr = h - lq + 31;  // in [0,62]; bias key-h index kh == lq
    f32x16 acc{};
#pragma unroll
    for (int c = 0; c < 4; ++c) {
      short8 bfr = *(const short8*)(th + tr * 64 + c * 16 + hi * 8);
      acc = __builtin_amdgcn_mfma_f32_32x32x16_bf16(qf[c], bfr, acc, 0, 0, 0);
    }
    float* O = rhp + (size_t)bh * 32768 + lq * 1024 + h * 32;
#pragma unroll
    for (int r = 0; r < 16; ++r) {
      const int w = (r & 3) + 8 * (r >> 2) + 4 * hi;  // q-row within h-block
      O[w] = acc[r] * 8.0f;
    }
  } else {
    const int r0 = lq;                          // j = lq
    const int r1 = (lq == 31) ? 62 : (32 + lq); // j = 32+lq (clamped; lq==31 unused)
    f32x16 a0{}, a1{};
#pragma unroll
    for (int c = 0; c < 4; ++c) {
      short8 b0 = *(const short8*)(tw + r0 * 64 + c * 16 + hi * 8);
      short8 b1 = *(const short8*)(tw + r1 * 64 + c * 16 + hi * 8);
      a0 = __builtin_amdgcn_mfma_f32_32x32x16_bf16(qf[c], b0, a0, 0, 0, 0);
      a1 = __builtin_amdgcn_mfma_f32_32x32x16_bf16(qf[c], b1, a1, 0, 0, 0);
    }
    float* O = rwp + (size_t)bh * 32768 + h * 32;
#pragma unroll
    for (int r = 0; r < 16; ++r) {
      const int w = (r & 3) + 8 * (r >> 2) + 4 * hi;
      const int k0i = w - lq + 31;  // from tile j=lq
      const int k1i = w - lq - 1;   // from tile j=32+lq
      if (k0i >= 0 && k0i < 32) O[k0i * 1024 + w] = a0[r] * 8.0f;
      if (k1i >= 0) O[k1i * 1024 + w] = a1[r] * 8.0f;
    }
  }
}

// ---------------- fused attention, 2-way split-K + K-register-prefetch ----------
// grid (48 bh, 16 qtiles64), 256 threads = 4 waves = (2 q-subtiles x 2 key-halves).
// ISSUE ORDER V(t) -> rh(t) -> K(t+1): vmcnt retires IN ORDER, so waiting on a
// load drains everything issued before it. R13's order (rh, K(t+1), V(t)) made
// PV's V-wait drain the just-issued K(t+1) prefetch -- paying the prefetch's
// full latency every tile. With V first, PV waits only on V (issued ~400cy
// earlier, covered), and K(t+1) keeps its full-tile slack. AITER's "never
// drain vmcnt to 0 in the main loop", achieved via issue order.
__global__ __launch_bounds__(256) void attn_kernel(
    const u16* __restrict__ pq, const u16* __restrict__ pk,
    const u16* __restrict__ pv, const float* __restrict__ rhp,
    const float* __restrict__ rwp, u16* __restrict__ aout) {
  const int bh = blockIdx.x, qt = blockIdx.y;
  const int tid = threadIdx.x, lane = tid & 63, wave = tid >> 6;
  const int wq = wave >> 1, wk = wave & 1;
  const int lq = lane & 31, hi = lane >> 5;
  const int q0 = qt * 64 + wq * 32;
  const u16* Qb = pq + (size_t)bh * 65536;
  const u16* Kb = pk + (size_t)bh * 65536;
  const u16* Vb = pv + (size_t)bh * 65536;
  const float* RH = rhp + (size_t)bh * 32768;
  const float* RW = rwp + (size_t)bh * 32768;
  __shared__ float part[2][2][64][17];  // [wq][wk][lane][r], stride-17 pad
  __shared__ float lsums[2][2][32];
  const int qg = q0 + lq;  // this lane's q row
  const int qsub = qt * 2 + wq;
  short8 qf[4];
#pragma unroll
  for (int c = 0; c < 4; ++c)
    qf[c] = *(const short8*)(Qb + ((qsub * 4 + c) * 64 + lane) * 8);
  float rw[16];
#pragma unroll
  for (int r = 0; r < 16; ++r)
    rw[r] = RW[((r & 3) + 8 * (r >> 2) + 4 * hi) * 1024 + qg];
  f32x16 o0{}, o1{};
  float lsum = 0.f;
  short8 kf[2][8];  // [tile parity][half*4 + c] prefetched K fragments
  {
    const int t0 = wk * 8;
#pragma unroll
    for (int c = 0; c < 4; ++c) {
      kf[0][c]     = *(const short8*)(Kb + (((t0 * 4 + c) * 2 + 0) * 64 + lane) * 8);
      kf[0][4 + c] = *(const short8*)(Kb + (((t0 * 4 + c) * 2 + 1) * 64 + lane) * 8);
    }
  }
#pragma unroll
  for (int t = 0; t < 8; ++t) {
    const int tt = wk * 8 + t;
    const int cur = t & 1, nxt = cur ^ 1;
    // (1) V(t) FIRST: its consumer (PV) then waits only on loads <= V(t).
    short8 vb0[4], vb1[4];
#pragma unroll
    for (int cc = 0; cc < 4; ++cc) {
      vb0[cc] = *(const short8*)(Vb + (((tt * 4 + cc) * 2 + 0) * 64 + lane) * 8);
      vb1[cc] = *(const short8*)(Vb + (((tt * 4 + cc) * 2 + 1) * 64 + lane) * 8);
    }
    // (2) rh(t): consumed at the exp stage (~300cy later), waits <= rh only.
    const float rh0 = RH[(tt * 2) * 1024 + qg];
    const float rh1 = RH[(tt * 2 + 1) * 1024 + qg];
    // (3) K(t+1) prefetch LAST: nothing this iteration waits on it.
    if (t < 7) {
      const int tn = tt + 1;
#pragma unroll
      for (int c = 0; c < 4; ++c) {
        kf[nxt][c]     = *(const short8*)(Kb + (((tn * 4 + c) * 2 + 0) * 64 + lane) * 8);
        kf[nxt][4 + c] = *(const short8*)(Kb + (((tn * 4 + c) * 2 + 1) * 64 + lane) * 8);
      }
    }
    // QK^T from zero C-init: K is in registers (prefetched) -> no wait
    f32x16 s0{}, s1{};
#pragma unroll
    for (int c = 0; c < 4; ++c) {
      s0 = __builtin_amdgcn_mfma_f32_32x32x16_bf16(kf[cur][c], qf[c], s0, 0, 0, 0);
      s1 = __builtin_amdgcn_mfma_f32_32x32x16_bf16(kf[cur][4 + c], qf[c], s1, 0, 0, 0);
    }
    // bias computed while MFMAs are in flight (depends only on rh + regs)
    float b0[16], b1[16];
#pragma unroll
    for (int r = 0; r < 16; ++r) { b0[r] = rh0 + rw[r]; b1[r] = rh1 + rw[r]; }
    // |S'| <= ~4.5 -> exp2 without max-subtract (log2e folded upstream)
#pragma unroll
    for (int r = 0; r < 16; ++r) {
      s0[r] = exp2f(s0[r] + b0[r]);
      s1[r] = exp2f(s1[r] + b1[r]);
    }
#pragma unroll
    for (int r = 0; r < 16; ++r) lsum += s0[r] + s1[r];
    // HW pack to bf16 + permlane half-exchange -> PV A-fragments (T12)
    unsigned int pw[16];
#pragma unroll
    for (int j = 0; j < 8; ++j) pw[j] = cvtpk(s0[2 * j], s0[2 * j + 1]);
#pragma unroll
    for (int j = 0; j < 8; ++j) pw[8 + j] = cvtpk(s1[2 * j], s1[2 * j + 1]);
    plswap(pw[0], pw[2]);  plswap(pw[1], pw[3]);
    plswap(pw[4], pw[6]);  plswap(pw[5], pw[7]);
    plswap(pw[8], pw[10]); plswap(pw[9], pw[11]);
    plswap(pw[12], pw[14]); plswap(pw[13], pw[15]);
#pragma unroll
    for (int cc = 0; cc < 4; ++cc) {
      uint4v w4 = {pw[cc * 4 + 0], pw[cc * 4 + 1], pw[cc * 4 + 2], pw[cc * 4 + 3]};
      short8 pa = __builtin_bit_cast(short8, w4);
      o0 = __builtin_amdgcn_mfma_f32_32x32x16_bf16(pa, vb0[cc], o0, 0, 0, 0);
      o1 = __builtin_amdgcn_mfma_f32_32x32x16_bf16(pa, vb1[cc], o1, 0, 0, 0);
    }
  }
  lsum += __shfl_xor(lsum, 32, 64);
  if (hi == 0) lsums[wq][wk][lq] = lsum;
  // store the O-half this wave will NOT finalize (wk==0 finalizes d<32 -> stores o1)
#pragma unroll
  for (int r = 0; r < 16; ++r)
    part[wq][wk][lane][r] = wk ? o0[r] : o1[r];
  __syncthreads();
  const int b = bh / 12, head = bh - b * 12;
  u16* outp = aout + (size_t)b * 1024 * 768 + head * 64 + wk * 32;
#pragma unroll
  for (int r = 0; r < 16; ++r) {
    const int qr = (r & 3) + 8 * (r >> 2) + 4 * hi;
    const float inv = 1.0f / (lsums[wq][0][qr] + lsums[wq][1][qr]);
    const float own = wk ? o1[r] : o0[r];
    const float val = own + part[wq][wk ^ 1][lane][r];
    outp[(size_t)(q0 + qr) * 768 + lq] = f2bf(val * inv);
  }
}

// ---------------- launch ----------------
extern "C" void kernel_launch(void* const* d_in, const int* in_sizes, int n_in,
                              void* d_out, int out_size, void* d_ws, size_t ws_size,
                              hipStream_t stream) {
  const float* x = (const float*)d_in[0];
  const float* qkv_w = (const float*)d_in[1];
  const float* qkv_b = (const float*)d_in[2];
  const float* proj_w = (const float*)d_in[3];
  const float* proj_b = (const float*)d_in[4];
  const float* rph = (const float*)d_in[5];
  const float* rpw = (const float*)d_in[6];
  float* out = (float*)d_out;
  char* ws = (char*)d_ws;
  u16* xb     = (u16*)(ws + 0);
  u16* wqkv   = (u16*)(ws + 6291456);
  u16* wproj  = (u16*)(ws + 9830400);
  u16* pq     = (u16*)(ws + 11010048);
  u16* pk     = (u16*)(ws + 17301504);
  u16* pv     = (u16*)(ws + 23592960);
  float* rhp  = (float*)(ws + 29884416);
  float* rwp  = (float*)(ws + 36175872);
  u16* aout   = (u16*)(ws + 42467328);
  u16* rphb   = (u16*)(ws + 48758784);
  u16* rpwb   = (u16*)(ws + 48766848);

  cvt_all<<<1024, 256, 0, stream>>>(x, xb, 3145728, qkv_w, wqkv, 1769472,
                                    proj_w, wproj, 589824, rph, rphb, 4032,
                                    rpw, rpwb, 4032);
  gemm128<0><<<dim3(18, 32), 256, 0, stream>>>(xb, wqkv, qkv_b, pq, pk, pv,
                                               nullptr, 4096, 2304, 768);
  rel_kernel<<<dim3(48, 32, 2), 64, 0, stream>>>(pq, rphb, rpwb, rhp, rwp);
  attn_kernel<<<dim3(48, 16), 256, 0, stream>>>(pq, pk, pv, rhp, rwp, aout);
  gemm128<1><<<dim3(6, 32), 256, 0, stream>>>(aout, wproj, proj_b, nullptr, nullptr,
                                              nullptr, out, 4096, 768, 768);
}